// Round 12
// baseline (415.215 us; speedup 1.0000x reference)
//
#include <hip/hip_runtime.h>
#include <math.h>

// Problem constants
#define NB 8
#define NT 2048
#define NC 128
#define NLM 64
#define NS 4
#define QROWS 2049
#define NCH 32  // 2048 / 64 chunks

#define TWO_LOG2E 2.885390081777927f
#define LOG2E_F 1.4426950408889634f

__device__ __forceinline__ float rcp_fast(float x) {
  return __builtin_amdgcn_rcpf(x);
}

__device__ __forceinline__ float readlane_f(float v, int lane) {
  return __int_as_float(__builtin_amdgcn_readlane(__float_as_int(v), lane));
}

// Raw v_exp_f32 (2^x). Safe here: |y| bounded ~12, far from denorm/inf
// edges where the libm denorm-guard sequence matters.
__device__ __forceinline__ float exp2_fast(float x) {
  float r;
  asm("v_exp_f32 %0, %1" : "=v"(r) : "v"(x));
  return r;
}

// ---------------------------------------------------------------------------
// Tiled 64-step local linear scan (forward substitution); all indices
// compile-time so q[4][16] stays in VGPRs. (Used by k23's logZ branch.)
// ---------------------------------------------------------------------------
template <typename PF, typename DF>
__device__ __forceinline__ void tri_scan64(PF P, DF D, float q[4][16]) {
#pragma unroll
  for (int tau = 0; tau < 4; ++tau) {
    float acc[16];
#pragma unroll
    for (int i = 0; i < 16; ++i) acc[i] = D(tau * 16 + i);
#pragma unroll
    for (int p = 0; p < 4; ++p) {
      if (p < tau) {
#pragma unroll
        for (int i = 0; i < 16; ++i) {
          const int t = tau * 16 + i;
#pragma unroll
          for (int i2 = 0; i2 < 16; ++i2) {
            acc[i] = fmaf(P(t, t - (p * 16 + i2) - 1), q[p][i2], acc[i]);
          }
        }
      }
    }
#pragma unroll
    for (int i = 0; i < 16; ++i) {
      const int t = tau * 16 + i;
#pragma unroll
      for (int i2 = 0; i2 < 16; ++i2) {
        if (i2 < i) acc[i] = fmaf(P(t, i - i2 - 1), q[tau][i2], acc[i]);
      }
      q[tau][i] = acc[i];
    }
  }
}

// K1 v2 (R22, measured): occupancy/latency fix confirmed — left top-5
// (<63us, was 63.8 at 41% busy / 17.6% occ).
__global__ __launch_bounds__(256) void k1_uv(
    const float* __restrict__ x, const float* __restrict__ W,
    const float* __restrict__ bias, const float* __restrict__ phiw,
    float* __restrict__ Q) {
  __shared__ __align__(16) float xs[16][128];  // 8 KB
  __shared__ float us[16][256];                // 16 KB
  const int tid = threadIdx.x;
  const int j = tid & 127;  // column
  const int h = tid >> 7;   // row-half: rows h*8 .. h*8+7
  const int r0 = h * 8;
  const int bt0 = blockIdx.x * 16;
  {
    // 16 rows x 128 cols = 512 float4; 256 threads -> 2 each
    const float4* x4 = (const float4*)(x + (long)bt0 * NC);
    ((float4*)xs)[tid] = x4[tid];
    ((float4*)xs)[tid + 256] = x4[tid + 256];
  }
  __syncthreads();
  float z[8];
  const float bj = bias[j];
#pragma unroll
  for (int r = 0; r < 8; ++r) z[r] = bj;
  for (int k = 0; k < 128; ++k) {
    float w = W[k * 128 + j];
#pragma unroll
    for (int r = 0; r < 8; ++r) z[r] = fmaf(xs[r0 + r][k], w, z[r]);
  }
  const float rs = 0.08838834764831845f;  // 1/sqrt(128)
#pragma unroll
  for (int r = 0; r < 8; ++r) {
    float sv, cv;
    sincosf(z[r], &sv, &cv);
    us[r0 + r][j] = cv * rs;
    us[r0 + r][128 + j] = sv * rs;
  }
  __syncthreads();
  float a[8];
#pragma unroll
  for (int r = 0; r < 8; ++r) a[r] = 0.f;
  for (int k = 0; k < 256; ++k) {
    float w = phiw[k * 128 + j];
#pragma unroll
    for (int r = 0; r < 8; ++r) a[r] = fmaf(us[r0 + r][k], w, a[r]);
  }
#pragma unroll
  for (int r = 0; r < 8; ++r) {
    int bt = bt0 + r0 + r;
    int b = bt >> 11, t = bt & 2047;
    Q[(b * QROWS + t + 1) * NC + j] = a[r];
  }
}

// K23 merged: blocks 0..255 = k2a (per-chunk raw sums of V);
//             blocks 256..259 = k3ab (serial logZ chunk evolution, per s).
__global__ __launch_bounds__(128) void k23_sums_logz(
    const float* __restrict__ Q, float* __restrict__ S2,
    const float* __restrict__ logw, float* __restrict__ logZt) {
  __shared__ float4 part[4][32];
  __shared__ float wx[64];
  __shared__ float mTs[64][65];
  __shared__ float Zr[64];
  const int x = blockIdx.x;
  const int tid = threadIdx.x;
  if (x < 256) {
    const int b = x >> 5, ch = x & 31;
    const int g = tid >> 5, c4 = tid & 31;
    const float4* Q4 = (const float4*)(Q + (long)(b * QROWS + ch * 64 + 1) * NC);
    float4 acc = make_float4(0.f, 0.f, 0.f, 0.f);
#pragma unroll
    for (int i = 0; i < 16; ++i) {
      float4 v = Q4[(g * 16 + i) * 32 + c4];
      acc.x += v.x; acc.y += v.y; acc.z += v.z; acc.w += v.w;
    }
    part[g][c4] = acc;
    __syncthreads();
    if (g == 0) {
      float4 p0 = part[0][c4], p1 = part[1][c4], p2 = part[2][c4], p3 = part[3][c4];
      ((float4*)(S2 + (long)(b * NCH + ch) * NC))[c4] =
          make_float4(p0.x + p1.x + p2.x + p3.x, p0.y + p1.y + p2.y + p3.y,
                      p0.z + p1.z + p2.z + p3.z, p0.w + p1.w + p2.w + p3.w);
    }
  } else {
    const int s = x - 256;
    const int j = tid;
    if (j < 64) wx[j] = __expf(logw[s * NLM + j]);
    __syncthreads();
    if (j < 64) {
      float q[4][16];
      tri_scan64([&](int t, int l) { return wx[l]; },
                 [&](int t) { int l = t + j; return (l < 64) ? wx[l] : 0.f; }, q);
#pragma unroll
      for (int tau = 0; tau < 4; ++tau)
#pragma unroll
        for (int i = 0; i < 16; ++i) mTs[j][tau * 16 + i] = q[tau][i];
    }
    const int t = j;
    if (t < 64) Zr[t] = (t == 0) ? 1.f : 0.f;
    if (t == 0) logZt[s * QROWS] = 0.f;
    float off = 0.f;
    __syncthreads();
    for (int ch = 0; ch < NCH; ++ch) {
      float acc = 0.f, mx = 0.f;
      if (t < 64) {
#pragma unroll 8
        for (int jj = 0; jj < 64; ++jj) acc = fmaf(mTs[jj][t], Zr[jj], acc);
        logZt[s * QROWS + ch * 64 + 1 + t] = logf(acc) + off;
        mx = acc;
#pragma unroll
        for (int o = 32; o; o >>= 1) mx = fmaxf(mx, __shfl_xor(mx, o));
      }
      __syncthreads();
      if (t < 64) {
        Zr[63 - t] = acc / mx;
        off += logf(mx);
      }
      __syncthreads();
    }
  }
}

// KB merged: blocks 0..127 = k5a_basis; blocks 128..383 = k2c (prefix fixup).
// Phase 0 uses the logsumexp identity: pi[t][l] = exp(lw[l] + logZ[t-l]
// - logZ[t+1]). Solve is the statically-tiled q[4][16] left-looking blocked
// substitution (R13).
__global__ __launch_bounds__(128) void kb_basis_fix(
    const float* __restrict__ logw, const float* __restrict__ logZt,
    float* __restrict__ pig, float* __restrict__ rt, float* __restrict__ ctT,
    float* __restrict__ klocal, float* __restrict__ Q,
    const float* __restrict__ S2) {
  // sbuf: [0,4096) psd (pi [t][l]); [4096,8192) Pts (Pt [t][t']);
  //       [8192,16384) Dl ([t][u], u=0..127). After the scan, Rl (stride 65)
  //       aliases [0,8192).
  __shared__ __align__(16) float sbuf[16384];  // 64 KB
  __shared__ float lzs[128];  // LOG2E * logZ[ch*64-63+i], i=0..127
  __shared__ float lws[64];   // LOG2E * logw
  __shared__ float4 gsum[4][32];
  float* psd = sbuf;
  float* Pts = sbuf + 4096;
  float* Dl = sbuf + 8192;
  float* Rl = sbuf;  // stride 65, valid after scan barrier
  const int x = blockIdx.x;
  const int tid = threadIdx.x;
  if (x < 128) {
    const int s = x >> 5, ch = x & 31;
    {
      int idx = ch * 64 - 63 + tid;  // max ch*64+64 <= 2048, in bounds
      lzs[tid] = (idx >= 0) ? logZt[s * QROWS + idx] * LOG2E_F : -INFINITY;
      if (tid < 64) lws[tid] = logw[s * NLM + tid] * LOG2E_F;
    }
    __syncthreads();
    {
      const int l = tid & 63, wv = tid >> 6;
      const float lw2 = lws[l];
      for (int tt = wv; tt < 64; tt += 2) {
        // la2 - lzn2 <= 0 by construction (logZ[t+1] = logsumexp of row)
        float e2 = lw2 + lzs[tt + 63 - l] - lzs[tt + 64];
        float pv = __builtin_exp2f(e2);
        psd[tt * 64 + l] = pv;
        pig[((long)s * NT + ch * 64 + tt) * NLM + l] = pv;
      }
    }
    __syncthreads();
    // Pt[t][t'] = psd[t][t-t'-1] (t'<t) else 0  (32 elems/thread)
    for (int i = tid; i < 4096; i += 128) {
      int t = i >> 6, tp = i & 63;
      Pts[i] = (tp < t) ? psd[t * 64 + (t - tp - 1)] : 0.f;
    }
    // Dl[t][u]: u<64 identity col u; u>=64 history col j=u-64 (64 elems/thread)
    for (int i = tid; i < 8192; i += 128) {
      int t = i >> 7, u = i & 127;
      float d;
      if (u < 64) {
        d = (t == u) ? 1.f : 0.f;
      } else {
        int l = t + (u - 64);
        d = (l < 64) ? psd[t * 64 + l] : 0.f;
      }
      Dl[i] = d;
    }
    __syncthreads();
    // unified forward substitution — statically tiled q[4][16], left-looking
    float q[4][16];
    const float* Dcol = Dl + tid;
#pragma unroll
    for (int tau = 0; tau < 4; ++tau) {
      float acc[16];
#pragma unroll
      for (int i = 0; i < 16; ++i) acc[i] = Dcol[(tau * 16 + i) * 128];
      // full 16x16 blocks from previous tiles (float4 broadcast loads)
#pragma unroll
      for (int p = 0; p < 4; ++p) {
        if (p < tau) {
#pragma unroll
          for (int i = 0; i < 16; ++i) {
            const int tr = tau * 16 + i;
            float a = acc[i];
#pragma unroll
            for (int q4 = 0; q4 < 4; ++q4) {
              float4 p4 = *(const float4*)&Pts[tr * 64 + p * 16 + q4 * 4];
              a = fmaf(p4.x, q[p][4 * q4 + 0], a);
              a = fmaf(p4.y, q[p][4 * q4 + 1], a);
              a = fmaf(p4.z, q[p][4 * q4 + 2], a);
              a = fmaf(p4.w, q[p][4 * q4 + 3], a);
            }
            acc[i] = a;
          }
        }
      }
      // serial intra-tile triangle (scalar broadcast loads)
#pragma unroll
      for (int i = 0; i < 16; ++i) {
        const int tr = tau * 16 + i;
        float a = acc[i];
#pragma unroll
        for (int i2 = 0; i2 < 16; ++i2) {
          if (i2 < i) a = fmaf(Pts[tr * 64 + tau * 16 + i2], q[tau][i2], a);
        }
        q[tau][i] = a;
      }
    }
    __syncthreads();  // psd/Pts dead; Rl may now alias them
    if (tid < 64) {
      const int tp = tid;  // impulse column
      float* rrow = rt + (((long)s * NCH + ch) * 64 + tp) * 64;  // [tp][t]
#pragma unroll
      for (int t4 = 0; t4 < 16; ++t4)
        ((float4*)rrow)[t4] = make_float4(
            q[t4 >> 2][4 * (t4 & 3) + 0], q[t4 >> 2][4 * (t4 & 3) + 1],
            q[t4 >> 2][4 * (t4 & 3) + 2], q[t4 >> 2][4 * (t4 & 3) + 3]);
#pragma unroll
      for (int tt = 0; tt < 4; ++tt)
#pragma unroll
        for (int i = 0; i < 16; ++i) Rl[tp * 65 + tt * 16 + i] = q[tt][i];
    } else {
      const int j = tid - 64;  // history lookback j+1
      float* ctb = ctT + ((long)s * NCH + ch) * 4096;  // [t][j]
#pragma unroll
      for (int tt = 0; tt < 4; ++tt)
#pragma unroll
        for (int i = 0; i < 16; ++i) ctb[(tt * 16 + i) * 64 + j] = q[tt][i];
    }
    __syncthreads();
    if (tid < 64) {  // klocal[t] = sum_tp R[t][tp]
      float acc = 0.f;
#pragma unroll 8
      for (int tp = 0; tp < 64; ++tp) acc += Rl[tp * 65 + tid];
      klocal[((long)s * NCH + ch) * 64 + tid] = acc;
    }
  } else {
    const int y = x - 128;
    const int b = y >> 5, ch = y & 31;
    const int g = tid >> 5, c4 = tid & 31;
    if (ch == 0 && g == 0)
      ((float4*)(Q + (long)(b * QROWS) * NC))[c4] = make_float4(0.f, 0.f, 0.f, 0.f);
    float4 run = make_float4(0.f, 0.f, 0.f, 0.f);
    for (int i = 0; i < ch; ++i) {
      float4 v = ((const float4*)(S2 + (long)(b * NCH + i) * NC))[c4];
      run.x += v.x; run.y += v.y; run.z += v.z; run.w += v.w;
    }
    float4* Q4 = (float4*)(Q + (long)(b * QROWS + ch * 64 + 1) * NC);
    float4 vbuf[16];
#pragma unroll
    for (int i = 0; i < 16; ++i) vbuf[i] = Q4[(g * 16 + i) * 32 + c4];
    {
      float4 gs = make_float4(0.f, 0.f, 0.f, 0.f);
#pragma unroll
      for (int i = 0; i < 16; ++i) {
        gs.x += vbuf[i].x; gs.y += vbuf[i].y; gs.z += vbuf[i].z; gs.w += vbuf[i].w;
      }
      gsum[g][c4] = gs;
    }
    __syncthreads();
    for (int gp = 0; gp < 3; ++gp) {
      if (gp < g) {
        float4 v = gsum[gp][c4];
        run.x += v.x; run.y += v.y; run.z += v.z; run.w += v.w;
      }
    }
#pragma unroll
    for (int i = 0; i < 16; ++i) {
      run.x += vbuf[i].x; run.y += vbuf[i].y; run.z += vbuf[i].z; run.w += vbuf[i].w;
      Q4[(g * 16 + i) * 32 + c4] = run;
    }
  }
}

// K4 v6 (R23, measured): scalar-path weights confirmed — left top-5
// (<61.3us, was 63.5). readfirstlane-proven-uniform pi rows lower to
// s_load; weights arrive as the fma's SGPR operand, zero readlanes.
__global__ __launch_bounds__(256) void k4_e(
    const float* __restrict__ Q, const float* __restrict__ pi,
    const float* __restrict__ phib, float* __restrict__ eq) {
  __shared__ float Qw[68][64];  // 17 KB
  const int b = blockIdx.x;
  const int t0 = blockIdx.y * 4;
  const int half = blockIdx.z;
  const int tid = threadIdx.x;
  for (int i = tid; i < 68 * 64; i += 256) {
    int r = i >> 6, cc = i & 63;
    int tau = t0 - 63 + r;
    Qw[r][cc] = (tau >= 0) ? Q[(b * QROWS + tau) * NC + half * 64 + cc] : 0.f;
  }
  const int c = tid & 63, tg = tid >> 6;  // c == lane id; tg == t-row
  // ti is wave-uniform (tg = tid>>6); readfirstlane makes that provable so
  // the weight loads scalarize to s_load (SGPR operands, no readlanes).
  const int ti = __builtin_amdgcn_readfirstlane(t0 + tg);
  const float* p0 = pi + ((long)0 * NT + ti) * NLM;
  const float* p1 = pi + ((long)1 * NT + ti) * NLM;
  const float* p2 = pi + ((long)2 * NT + ti) * NLM;
  const float* p3 = pi + ((long)3 * NT + ti) * NLM;
  __syncthreads();
  const float pb2 = phib[half * 64 + c] * TWO_LOG2E;
  const float Qt = Qw[tg + 64][c];
  float a0 = 0.f, a1 = 0.f, a2 = 0.f, a3 = 0.f;
#pragma unroll
  for (int lc = 0; lc < 4; ++lc) {
    float v[16];
#pragma unroll
    for (int u = 0; u < 16; ++u) {
      const int l = lc * 16 + u;
      const float cl = TWO_LOG2E / (float)(l + 9);  // folded constant
      float y = (Qt - Qw[tg + 63 - l][c]) * cl + pb2;
      v[u] = rcp_fast(exp2_fast(y) + 1.f);
    }
#pragma unroll
    for (int u = 0; u < 16; ++u) {
      const int l = lc * 16 + u;
      a0 = fmaf(p0[l], v[u], a0);
      a1 = fmaf(p1[l], v[u], a1);
      a2 = fmaf(p2[l], v[u], a2);
      a3 = fmaf(p3[l], v[u], a3);
    }
  }
  const long base = half * 64 + c;
  eq[((long)(0 * 8 + b) * NT + ti) * NC + base] = fmaf(-2.f, a0, 1.f);
  eq[((long)(1 * 8 + b) * NT + ti) * NC + base] = fmaf(-2.f, a1, 1.f);
  eq[((long)(2 * 8 + b) * NT + ti) * NC + base] = fmaf(-2.f, a2, 1.f);
  eq[((long)(3 * 8 + b) * NT + ti) * NC + base] = fmaf(-2.f, a3, 1.f);
}

// K5a-data: qlocal = R @ e per (s,b,chunk) — tiled GEMM, 8t x 8c per lane.
__global__ __launch_bounds__(128) void k5a_data(const float* __restrict__ rt,
                                                float* __restrict__ eq) {
  __shared__ __align__(16) float rts[4096];    // [tp][t] 16 KB
  __shared__ __align__(16) float es[64][128];  // 32 KB
  const int sb = blockIdx.x;  // s*8+b
  const int s = sb >> 3;
  const int ch = blockIdx.y;
  const int tid = threadIdx.x;
  const float4* rsrc = (const float4*)(rt + ((long)s * NCH + ch) * 4096);
#pragma unroll
  for (int i = 0; i < 8; ++i) ((float4*)rts)[tid + 128 * i] = rsrc[tid + 128 * i];
  float* qb = eq + ((long)sb * NT + ch * 64) * NC;
  const float4* esrc = (const float4*)qb;
#pragma unroll
  for (int i = 0; i < 16; ++i) ((float4*)es)[tid + 128 * i] = esrc[tid + 128 * i];
  __syncthreads();
  const int t0 = (tid >> 4) * 8;  // 8 t-tiles
  const int c0 = (tid & 15) * 8;  // 16 c-tiles
  float acc[8][8];
#pragma unroll
  for (int i = 0; i < 8; ++i)
#pragma unroll
    for (int k = 0; k < 8; ++k) acc[i][k] = 0.f;
  for (int tp = 0; tp < 64; ++tp) {
    if (tp <= t0 + 7) {  // R is lower-triangular
      float4 r0 = *(const float4*)&rts[tp * 64 + t0];
      float4 r1 = *(const float4*)&rts[tp * 64 + t0 + 4];
      float4 e0 = *(const float4*)&es[tp][c0];
      float4 e1 = *(const float4*)&es[tp][c0 + 4];
      float rr[8] = {r0.x, r0.y, r0.z, r0.w, r1.x, r1.y, r1.z, r1.w};
      float ee[8] = {e0.x, e0.y, e0.z, e0.w, e1.x, e1.y, e1.z, e1.w};
#pragma unroll
      for (int i = 0; i < 8; ++i)
#pragma unroll
        for (int k = 0; k < 8; ++k) acc[i][k] = fmaf(rr[i], ee[k], acc[i][k]);
    }
  }
#pragma unroll
  for (int i = 0; i < 8; ++i) {
    float4* dst = (float4*)(qb + (t0 + i) * NC + c0);
    dst[0] = make_float4(acc[i][0], acc[i][1], acc[i][2], acc[i][3]);
    dst[1] = make_float4(acc[i][4], acc[i][5], acc[i][6], acc[i][7]);
  }
}

// K5b v2 (R13): cross-chunk combine; cr chunk staged once per block through
// padded LDS (stride 65 => conflict-free), double-buffered across chunks;
// 4 waves per block, 4 channels per wave. History h broadcast via
// v_readlane. Blocks 0..255 = q-scan; blocks 256..259 = k-scan.
__global__ __launch_bounds__(256) void k5b_scan(const float* __restrict__ ctT,
                                                const float* __restrict__ klocal,
                                                float* __restrict__ eq,
                                                float* __restrict__ kout) {
  __shared__ float crs[2][64 * 65];  // 32.5 KB, padded stride 65
  const int tid = threadIdx.x;
  const int t = tid & 63;
  const int w = tid >> 6;
  const int bid = blockIdx.x;
  const bool isq = bid < 256;
  const int s = isq ? ((bid & 7) >> 1) : (bid - 256);
  const float* ctTs = ctT + (long)s * NCH * 4096;

  // staging geometry: thread -> (row sr, 16-float quarter sq); 16 floats each
  const int sr = tid >> 2;
  const int sq = (tid & 3) * 16;
  float4 stg0, stg1, stg2, stg3;

#define K5B_STAGE_LOAD(CH)                                                    \
  {                                                                           \
    const float4* p_ = (const float4*)(ctTs + (CH)*4096 + sr * 64 + sq);      \
    stg0 = p_[0]; stg1 = p_[1]; stg2 = p_[2]; stg3 = p_[3];                   \
  }
#define K5B_STAGE_WRITE(BUF)                                                  \
  {                                                                           \
    float* d_ = &crs[BUF][sr * 65 + sq];                                      \
    d_[0] = stg0.x;  d_[1] = stg0.y;  d_[2] = stg0.z;  d_[3] = stg0.w;        \
    d_[4] = stg1.x;  d_[5] = stg1.y;  d_[6] = stg1.z;  d_[7] = stg1.w;        \
    d_[8] = stg2.x;  d_[9] = stg2.y;  d_[10] = stg2.z; d_[11] = stg2.w;       \
    d_[12] = stg3.x; d_[13] = stg3.y; d_[14] = stg3.z; d_[15] = stg3.w;       \
  }

  // q-branch mapping: per (s,b) 8 blocks x 4 waves x 4 channels = 128 ch
  const int g = bid >> 3;
  const int bb = g & 7, pp = g >> 3;  // pp 0..3 (q-blocks)
  const int hp = bid & 1;
  const int c0 = ((((pp << 1) | hp) << 2) | w) * 4;  // slice*4, slice 0..31
  const int sb = s * 8 + bb;
  float* eqb = eq + (long)sb * NT * NC + c0;

  float hv0 = 0.f, hv1 = 0.f, hv2 = 0.f, hv3 = 0.f;  // q history (per lane t)
  float hk = 0.f;                                    // k history

  K5B_STAGE_LOAD(0)
  K5B_STAGE_WRITE(0)
  __syncthreads();
#pragma unroll 1
  for (int ch = 0; ch < NCH; ++ch) {
    const int cur = ch & 1;
    if (ch + 1 < NCH) K5B_STAGE_LOAD(ch + 1)  // issue early; lands at write
    if (isq) {
      const float* cr = &crs[cur][t * 65];
      float4 ql = *(const float4*)(eqb + (long)(ch * 64 + t) * NC);
      float a0 = 0.f, a1 = 0.f, a2 = 0.f, a3 = 0.f;
#pragma unroll
      for (int j = 0; j < 64; ++j) {
        float cv = cr[j];
        a0 = fmaf(cv, readlane_f(hv0, 63 - j), a0);
        a1 = fmaf(cv, readlane_f(hv1, 63 - j), a1);
        a2 = fmaf(cv, readlane_f(hv2, 63 - j), a2);
        a3 = fmaf(cv, readlane_f(hv3, 63 - j), a3);
      }
      hv0 = a0 + ql.x; hv1 = a1 + ql.y; hv2 = a2 + ql.z; hv3 = a3 + ql.w;
      *(float4*)(eqb + (long)(ch * 64 + t) * NC) =
          make_float4(hv0, hv1, hv2, hv3);
    } else if (tid < 64) {
      const float* cr = &crs[cur][t * 65];
      float acc = klocal[((long)s * NCH + ch) * 64 + t];
#pragma unroll
      for (int j = 0; j < 64; ++j)
        acc = fmaf(cr[j], readlane_f(hk, 63 - j), acc);
      kout[s * NT + ch * 64 + t] = acc;
      hk = acc;
    }
    __syncthreads();  // all waves done READING crs[cur^1] (chunk ch-1)
    if (ch + 1 < NCH) K5B_STAGE_WRITE(cur ^ 1)
    __syncthreads();  // crs[cur^1] ready for chunk ch+1
  }
#undef K5B_STAGE_LOAD
#undef K5B_STAGE_WRITE
}

// K6 v2 (R24): MAC-tile rebalance + occupancy. R23 profile: 61.4us,
// VALUBusy 65%, Occupancy 30%. Old thread tile (8 rows x 1 col) issued
// 1024 broadcast ds_read_b128/thread (1 per 4 fma) — the k4 disease.
// New tile: 2 rows x 2 contiguous cols per thread => each b128 feeds 8
// fma (256 LDS instr/thread, 4x fewer); mixw as coalesced float2.
// Block tile 16->8 rows: LDS 32->16KB, grid 1024->2048 = 8 blocks/CU
// (R20/R22 occupancy lever). All rsdata reads remain wave-uniform
// broadcasts (tg = tid>>6 wave-uniform) => conflict-free. Accumulators
// are 4 named scalars (rule #20).
__global__ __launch_bounds__(256) void k6_mix(
    const float* __restrict__ q, const float* __restrict__ kout,
    const float* __restrict__ anchor, const float* __restrict__ mixw,
    const float* __restrict__ mixb, float* __restrict__ out) {
  __shared__ __align__(16) float rsdata[8][512];  // 16 KB
  const int b = blockIdx.x;
  const int t0 = blockIdx.y * 8;
  const int tid = threadIdx.x;
  for (int i = tid; i < 8 * 512; i += 256) {
    int r = i >> 9, sc = i & 511;
    int s = sc >> 7, c = sc & 127;
    int ti = t0 + r;
    float qv = q[((long)(s * 8 + b) * NT + ti) * NC + c];
    float kv = kout[s * NT + ti];
    float d1 = rcp_fast(kv + 16.f);
    rsdata[r][sc] = (qv + 16.f * anchor[sc]) * d1 * (kv * d1);
  }
  __syncthreads();
  const int c2 = (tid & 63) * 2;  // contiguous col pair c2, c2+1
  const int tg = tid >> 6;        // wave-uniform: 4 groups x 2 rows
  const int r0 = tg * 2;
  float acc00 = mixb[c2], acc01 = mixb[c2 + 1];
  float acc10 = acc00, acc11 = acc01;
  for (int kk = 0; kk < 512; kk += 4) {
    float4 rv0 = *(const float4*)&rsdata[r0][kk];      // broadcast
    float4 rv1 = *(const float4*)&rsdata[r0 + 1][kk];  // broadcast
    float2 w0 = *(const float2*)&mixw[(kk + 0) * 128 + c2];
    float2 w1 = *(const float2*)&mixw[(kk + 1) * 128 + c2];
    float2 w2 = *(const float2*)&mixw[(kk + 2) * 128 + c2];
    float2 w3 = *(const float2*)&mixw[(kk + 3) * 128 + c2];
    acc00 = fmaf(rv0.x, w0.x, acc00); acc01 = fmaf(rv0.x, w0.y, acc01);
    acc10 = fmaf(rv1.x, w0.x, acc10); acc11 = fmaf(rv1.x, w0.y, acc11);
    acc00 = fmaf(rv0.y, w1.x, acc00); acc01 = fmaf(rv0.y, w1.y, acc01);
    acc10 = fmaf(rv1.y, w1.x, acc10); acc11 = fmaf(rv1.y, w1.y, acc11);
    acc00 = fmaf(rv0.z, w2.x, acc00); acc01 = fmaf(rv0.z, w2.y, acc01);
    acc10 = fmaf(rv1.z, w2.x, acc10); acc11 = fmaf(rv1.z, w2.y, acc11);
    acc00 = fmaf(rv0.w, w3.x, acc00); acc01 = fmaf(rv0.w, w3.y, acc01);
    acc10 = fmaf(rv1.w, w3.x, acc10); acc11 = fmaf(rv1.w, w3.y, acc11);
  }
  float* o0 = out + ((long)b * NT + t0 + r0) * NC + c2;
  float* o1 = out + ((long)b * NT + t0 + r0 + 1) * NC + c2;
  *(float2*)o0 = make_float2(acc00, acc01);
  *(float2*)o1 = make_float2(acc10, acc11);
}

extern "C" void kernel_launch(void* const* d_in, const int* in_sizes, int n_in,
                              void* d_out, int out_size, void* d_ws, size_t ws_size,
                              hipStream_t stream) {
  const float* x = (const float*)d_in[0];
  const float* W = (const float*)d_in[1];
  const float* bias = (const float*)d_in[2];
  const float* phiw = (const float*)d_in[3];
  const float* phib = (const float*)d_in[4];
  const float* anchor = (const float*)d_in[5];
  const float* logw = (const float*)d_in[6];
  const float* mixw = (const float*)d_in[7];
  const float* mixb = (const float*)d_in[8];
  float* out = (float*)d_out;

  float* ws = (float*)d_ws;
  float* Q = ws;                                     // 8*2049*128 = 2,098,176
  float* pi = Q + (long)NB * QROWS * NC;             // 4*2048*64  =   524,288
  float* eq = pi + (long)NS * NT * NLM;              // 32*2048*128= 8,388,608
  float* coefTT = eq + (long)NS * NB * NT * NC;      //               524,288
  float* rtb = coefTT + (long)NS * NCH * 4096;       //               524,288
  float* klocal = rtb + (long)NS * NCH * 4096;       //                 8,192
  float* kout = klocal + (long)NS * NCH * 64;        //                 8,192
  float* logZt = kout + (long)NS * NT;               //                 8,196
  float* S2 = logZt + (long)NS * QROWS;              //                32,768

  hipLaunchKernelGGL(k1_uv, dim3(NB * NT / 16), dim3(256), 0, stream, x, W, bias, phiw, Q);
  hipLaunchKernelGGL(k23_sums_logz, dim3(260), dim3(128), 0, stream, Q, S2, logw, logZt);
  hipLaunchKernelGGL(kb_basis_fix, dim3(384), dim3(128), 0, stream, logw, logZt, pi, rtb, coefTT, klocal, Q, S2);
  hipLaunchKernelGGL(k4_e, dim3(NB, NT / 4, 2), dim3(256), 0, stream, Q, pi, phib, eq);
  hipLaunchKernelGGL(k5a_data, dim3(NS * NB, NCH), dim3(128), 0, stream, rtb, eq);
  hipLaunchKernelGGL(k5b_scan, dim3(260), dim3(256), 0, stream, coefTT, klocal, eq, kout);
  hipLaunchKernelGGL(k6_mix, dim3(NB, NT / 8), dim3(256), 0, stream, eq, kout, anchor, mixw, mixb, out);
}

// Round 14
// 348.285 us; speedup vs baseline: 1.1922x; 1.1922x over previous
//
#include <hip/hip_runtime.h>
#include <math.h>

// Problem constants
#define NB 8
#define NT 2048
#define NC 128
#define NLM 64
#define NS 4
#define QROWS 2049
#define NCH 32  // 2048 / 64 chunks

#define TWO_LOG2E 2.885390081777927f
#define LOG2E_F 1.4426950408889634f

__device__ __forceinline__ float rcp_fast(float x) {
  return __builtin_amdgcn_rcpf(x);
}

__device__ __forceinline__ float readlane_f(float v, int lane) {
  return __int_as_float(__builtin_amdgcn_readlane(__float_as_int(v), lane));
}

// Raw v_exp_f32 (2^x). Safe here: |y| bounded ~12, far from denorm/inf
// edges where the libm denorm-guard sequence matters.
__device__ __forceinline__ float exp2_fast(float x) {
  float r;
  asm("v_exp_f32 %0, %1" : "=v"(r) : "v"(x));
  return r;
}

// ---------------------------------------------------------------------------
// Tiled 64-step local linear scan (forward substitution); all indices
// compile-time so q[4][16] stays in VGPRs. (Used by k23's logZ branch.)
// ---------------------------------------------------------------------------
template <typename PF, typename DF>
__device__ __forceinline__ void tri_scan64(PF P, DF D, float q[4][16]) {
#pragma unroll
  for (int tau = 0; tau < 4; ++tau) {
    float acc[16];
#pragma unroll
    for (int i = 0; i < 16; ++i) acc[i] = D(tau * 16 + i);
#pragma unroll
    for (int p = 0; p < 4; ++p) {
      if (p < tau) {
#pragma unroll
        for (int i = 0; i < 16; ++i) {
          const int t = tau * 16 + i;
#pragma unroll
          for (int i2 = 0; i2 < 16; ++i2) {
            acc[i] = fmaf(P(t, t - (p * 16 + i2) - 1), q[p][i2], acc[i]);
          }
        }
      }
    }
#pragma unroll
    for (int i = 0; i < 16; ++i) {
      const int t = tau * 16 + i;
#pragma unroll
      for (int i2 = 0; i2 < 16; ++i2) {
        if (i2 < i) acc[i] = fmaf(P(t, i - i2 - 1), q[tau][i2], acc[i]);
      }
      q[tau][i] = acc[i];
    }
  }
}

// K1 v2 (R22, measured): occupancy/latency fix confirmed — left top-5
// (<63us, was 63.8 at 41% busy / 17.6% occ).
__global__ __launch_bounds__(256) void k1_uv(
    const float* __restrict__ x, const float* __restrict__ W,
    const float* __restrict__ bias, const float* __restrict__ phiw,
    float* __restrict__ Q) {
  __shared__ __align__(16) float xs[16][128];  // 8 KB
  __shared__ float us[16][256];                // 16 KB
  const int tid = threadIdx.x;
  const int j = tid & 127;  // column
  const int h = tid >> 7;   // row-half: rows h*8 .. h*8+7
  const int r0 = h * 8;
  const int bt0 = blockIdx.x * 16;
  {
    // 16 rows x 128 cols = 512 float4; 256 threads -> 2 each
    const float4* x4 = (const float4*)(x + (long)bt0 * NC);
    ((float4*)xs)[tid] = x4[tid];
    ((float4*)xs)[tid + 256] = x4[tid + 256];
  }
  __syncthreads();
  float z[8];
  const float bj = bias[j];
#pragma unroll
  for (int r = 0; r < 8; ++r) z[r] = bj;
  for (int k = 0; k < 128; ++k) {
    float w = W[k * 128 + j];
#pragma unroll
    for (int r = 0; r < 8; ++r) z[r] = fmaf(xs[r0 + r][k], w, z[r]);
  }
  const float rs = 0.08838834764831845f;  // 1/sqrt(128)
#pragma unroll
  for (int r = 0; r < 8; ++r) {
    float sv, cv;
    sincosf(z[r], &sv, &cv);
    us[r0 + r][j] = cv * rs;
    us[r0 + r][128 + j] = sv * rs;
  }
  __syncthreads();
  float a[8];
#pragma unroll
  for (int r = 0; r < 8; ++r) a[r] = 0.f;
  for (int k = 0; k < 256; ++k) {
    float w = phiw[k * 128 + j];
#pragma unroll
    for (int r = 0; r < 8; ++r) a[r] = fmaf(us[r0 + r][k], w, a[r]);
  }
#pragma unroll
  for (int r = 0; r < 8; ++r) {
    int bt = bt0 + r0 + r;
    int b = bt >> 11, t = bt & 2047;
    Q[(b * QROWS + t + 1) * NC + j] = a[r];
  }
}

// K23 merged: blocks 0..255 = k2a (per-chunk raw sums of V);
//             blocks 256..259 = k3ab (serial logZ chunk evolution, per s).
__global__ __launch_bounds__(128) void k23_sums_logz(
    const float* __restrict__ Q, float* __restrict__ S2,
    const float* __restrict__ logw, float* __restrict__ logZt) {
  __shared__ float4 part[4][32];
  __shared__ float wx[64];
  __shared__ float mTs[64][65];
  __shared__ float Zr[64];
  const int x = blockIdx.x;
  const int tid = threadIdx.x;
  if (x < 256) {
    const int b = x >> 5, ch = x & 31;
    const int g = tid >> 5, c4 = tid & 31;
    const float4* Q4 = (const float4*)(Q + (long)(b * QROWS + ch * 64 + 1) * NC);
    float4 acc = make_float4(0.f, 0.f, 0.f, 0.f);
#pragma unroll
    for (int i = 0; i < 16; ++i) {
      float4 v = Q4[(g * 16 + i) * 32 + c4];
      acc.x += v.x; acc.y += v.y; acc.z += v.z; acc.w += v.w;
    }
    part[g][c4] = acc;
    __syncthreads();
    if (g == 0) {
      float4 p0 = part[0][c4], p1 = part[1][c4], p2 = part[2][c4], p3 = part[3][c4];
      ((float4*)(S2 + (long)(b * NCH + ch) * NC))[c4] =
          make_float4(p0.x + p1.x + p2.x + p3.x, p0.y + p1.y + p2.y + p3.y,
                      p0.z + p1.z + p2.z + p3.z, p0.w + p1.w + p2.w + p3.w);
    }
  } else {
    const int s = x - 256;
    const int j = tid;
    if (j < 64) wx[j] = __expf(logw[s * NLM + j]);
    __syncthreads();
    if (j < 64) {
      float q[4][16];
      tri_scan64([&](int t, int l) { return wx[l]; },
                 [&](int t) { int l = t + j; return (l < 64) ? wx[l] : 0.f; }, q);
#pragma unroll
      for (int tau = 0; tau < 4; ++tau)
#pragma unroll
        for (int i = 0; i < 16; ++i) mTs[j][tau * 16 + i] = q[tau][i];
    }
    const int t = j;
    if (t < 64) Zr[t] = (t == 0) ? 1.f : 0.f;
    if (t == 0) logZt[s * QROWS] = 0.f;
    float off = 0.f;
    __syncthreads();
    for (int ch = 0; ch < NCH; ++ch) {
      float acc = 0.f, mx = 0.f;
      if (t < 64) {
#pragma unroll 8
        for (int jj = 0; jj < 64; ++jj) acc = fmaf(mTs[jj][t], Zr[jj], acc);
        logZt[s * QROWS + ch * 64 + 1 + t] = logf(acc) + off;
        mx = acc;
#pragma unroll
        for (int o = 32; o; o >>= 1) mx = fmaxf(mx, __shfl_xor(mx, o));
      }
      __syncthreads();
      if (t < 64) {
        Zr[63 - t] = acc / mx;
        off += logf(mx);
      }
      __syncthreads();
    }
  }
}

// KB merged: blocks 0..127 = k5a_basis; blocks 128..383 = k2c (prefix fixup).
// Phase 0 uses the logsumexp identity: pi[t][l] = exp(lw[l] + logZ[t-l]
// - logZ[t+1]). Solve is the statically-tiled q[4][16] left-looking blocked
// substitution (R13).
__global__ __launch_bounds__(128) void kb_basis_fix(
    const float* __restrict__ logw, const float* __restrict__ logZt,
    float* __restrict__ pig, float* __restrict__ rt, float* __restrict__ ctT,
    float* __restrict__ klocal, float* __restrict__ Q,
    const float* __restrict__ S2) {
  // sbuf: [0,4096) psd (pi [t][l]); [4096,8192) Pts (Pt [t][t']);
  //       [8192,16384) Dl ([t][u], u=0..127). After the scan, Rl (stride 65)
  //       aliases [0,8192).
  __shared__ __align__(16) float sbuf[16384];  // 64 KB
  __shared__ float lzs[128];  // LOG2E * logZ[ch*64-63+i], i=0..127
  __shared__ float lws[64];   // LOG2E * logw
  __shared__ float4 gsum[4][32];
  float* psd = sbuf;
  float* Pts = sbuf + 4096;
  float* Dl = sbuf + 8192;
  float* Rl = sbuf;  // stride 65, valid after scan barrier
  const int x = blockIdx.x;
  const int tid = threadIdx.x;
  if (x < 128) {
    const int s = x >> 5, ch = x & 31;
    {
      int idx = ch * 64 - 63 + tid;  // max ch*64+64 <= 2048, in bounds
      lzs[tid] = (idx >= 0) ? logZt[s * QROWS + idx] * LOG2E_F : -INFINITY;
      if (tid < 64) lws[tid] = logw[s * NLM + tid] * LOG2E_F;
    }
    __syncthreads();
    {
      const int l = tid & 63, wv = tid >> 6;
      const float lw2 = lws[l];
      for (int tt = wv; tt < 64; tt += 2) {
        // la2 - lzn2 <= 0 by construction (logZ[t+1] = logsumexp of row)
        float e2 = lw2 + lzs[tt + 63 - l] - lzs[tt + 64];
        float pv = __builtin_exp2f(e2);
        psd[tt * 64 + l] = pv;
        pig[((long)s * NT + ch * 64 + tt) * NLM + l] = pv;
      }
    }
    __syncthreads();
    // Pt[t][t'] = psd[t][t-t'-1] (t'<t) else 0  (32 elems/thread)
    for (int i = tid; i < 4096; i += 128) {
      int t = i >> 6, tp = i & 63;
      Pts[i] = (tp < t) ? psd[t * 64 + (t - tp - 1)] : 0.f;
    }
    // Dl[t][u]: u<64 identity col u; u>=64 history col j=u-64 (64 elems/thread)
    for (int i = tid; i < 8192; i += 128) {
      int t = i >> 7, u = i & 127;
      float d;
      if (u < 64) {
        d = (t == u) ? 1.f : 0.f;
      } else {
        int l = t + (u - 64);
        d = (l < 64) ? psd[t * 64 + l] : 0.f;
      }
      Dl[i] = d;
    }
    __syncthreads();
    // unified forward substitution — statically tiled q[4][16], left-looking
    float q[4][16];
    const float* Dcol = Dl + tid;
#pragma unroll
    for (int tau = 0; tau < 4; ++tau) {
      float acc[16];
#pragma unroll
      for (int i = 0; i < 16; ++i) acc[i] = Dcol[(tau * 16 + i) * 128];
      // full 16x16 blocks from previous tiles (float4 broadcast loads)
#pragma unroll
      for (int p = 0; p < 4; ++p) {
        if (p < tau) {
#pragma unroll
          for (int i = 0; i < 16; ++i) {
            const int tr = tau * 16 + i;
            float a = acc[i];
#pragma unroll
            for (int q4 = 0; q4 < 4; ++q4) {
              float4 p4 = *(const float4*)&Pts[tr * 64 + p * 16 + q4 * 4];
              a = fmaf(p4.x, q[p][4 * q4 + 0], a);
              a = fmaf(p4.y, q[p][4 * q4 + 1], a);
              a = fmaf(p4.z, q[p][4 * q4 + 2], a);
              a = fmaf(p4.w, q[p][4 * q4 + 3], a);
            }
            acc[i] = a;
          }
        }
      }
      // serial intra-tile triangle (scalar broadcast loads)
#pragma unroll
      for (int i = 0; i < 16; ++i) {
        const int tr = tau * 16 + i;
        float a = acc[i];
#pragma unroll
        for (int i2 = 0; i2 < 16; ++i2) {
          if (i2 < i) a = fmaf(Pts[tr * 64 + tau * 16 + i2], q[tau][i2], a);
        }
        q[tau][i] = a;
      }
    }
    __syncthreads();  // psd/Pts dead; Rl may now alias them
    if (tid < 64) {
      const int tp = tid;  // impulse column
      float* rrow = rt + (((long)s * NCH + ch) * 64 + tp) * 64;  // [tp][t]
#pragma unroll
      for (int t4 = 0; t4 < 16; ++t4)
        ((float4*)rrow)[t4] = make_float4(
            q[t4 >> 2][4 * (t4 & 3) + 0], q[t4 >> 2][4 * (t4 & 3) + 1],
            q[t4 >> 2][4 * (t4 & 3) + 2], q[t4 >> 2][4 * (t4 & 3) + 3]);
#pragma unroll
      for (int tt = 0; tt < 4; ++tt)
#pragma unroll
        for (int i = 0; i < 16; ++i) Rl[tp * 65 + tt * 16 + i] = q[tt][i];
    } else {
      const int j = tid - 64;  // history lookback j+1
      float* ctb = ctT + ((long)s * NCH + ch) * 4096;  // [t][j]
#pragma unroll
      for (int tt = 0; tt < 4; ++tt)
#pragma unroll
        for (int i = 0; i < 16; ++i) ctb[(tt * 16 + i) * 64 + j] = q[tt][i];
    }
    __syncthreads();
    if (tid < 64) {  // klocal[t] = sum_tp R[t][tp]
      float acc = 0.f;
#pragma unroll 8
      for (int tp = 0; tp < 64; ++tp) acc += Rl[tp * 65 + tid];
      klocal[((long)s * NCH + ch) * 64 + tid] = acc;
    }
  } else {
    const int y = x - 128;
    const int b = y >> 5, ch = y & 31;
    const int g = tid >> 5, c4 = tid & 31;
    if (ch == 0 && g == 0)
      ((float4*)(Q + (long)(b * QROWS) * NC))[c4] = make_float4(0.f, 0.f, 0.f, 0.f);
    float4 run = make_float4(0.f, 0.f, 0.f, 0.f);
    for (int i = 0; i < ch; ++i) {
      float4 v = ((const float4*)(S2 + (long)(b * NCH + i) * NC))[c4];
      run.x += v.x; run.y += v.y; run.z += v.z; run.w += v.w;
    }
    float4* Q4 = (float4*)(Q + (long)(b * QROWS + ch * 64 + 1) * NC);
    float4 vbuf[16];
#pragma unroll
    for (int i = 0; i < 16; ++i) vbuf[i] = Q4[(g * 16 + i) * 32 + c4];
    {
      float4 gs = make_float4(0.f, 0.f, 0.f, 0.f);
#pragma unroll
      for (int i = 0; i < 16; ++i) {
        gs.x += vbuf[i].x; gs.y += vbuf[i].y; gs.z += vbuf[i].z; gs.w += vbuf[i].w;
      }
      gsum[g][c4] = gs;
    }
    __syncthreads();
    for (int gp = 0; gp < 3; ++gp) {
      if (gp < g) {
        float4 v = gsum[gp][c4];
        run.x += v.x; run.y += v.y; run.z += v.z; run.w += v.w;
      }
    }
#pragma unroll
    for (int i = 0; i < 16; ++i) {
      run.x += vbuf[i].x; run.y += vbuf[i].y; run.z += vbuf[i].z; run.w += vbuf[i].w;
      Q4[(g * 16 + i) * 32 + c4] = run;
    }
  }
}

// K4 v6 (R23, measured): scalar-path weights confirmed — left top-5
// (<61.3us, was 63.5). readfirstlane-proven-uniform pi rows lower to
// s_load; weights arrive as the fma's SGPR operand, zero readlanes.
__global__ __launch_bounds__(256) void k4_e(
    const float* __restrict__ Q, const float* __restrict__ pi,
    const float* __restrict__ phib, float* __restrict__ eq) {
  __shared__ float Qw[68][64];  // 17 KB
  const int b = blockIdx.x;
  const int t0 = blockIdx.y * 4;
  const int half = blockIdx.z;
  const int tid = threadIdx.x;
  for (int i = tid; i < 68 * 64; i += 256) {
    int r = i >> 6, cc = i & 63;
    int tau = t0 - 63 + r;
    Qw[r][cc] = (tau >= 0) ? Q[(b * QROWS + tau) * NC + half * 64 + cc] : 0.f;
  }
  const int c = tid & 63, tg = tid >> 6;  // c == lane id; tg == t-row
  // ti is wave-uniform (tg = tid>>6); readfirstlane makes that provable so
  // the weight loads scalarize to s_load (SGPR operands, no readlanes).
  const int ti = __builtin_amdgcn_readfirstlane(t0 + tg);
  const float* p0 = pi + ((long)0 * NT + ti) * NLM;
  const float* p1 = pi + ((long)1 * NT + ti) * NLM;
  const float* p2 = pi + ((long)2 * NT + ti) * NLM;
  const float* p3 = pi + ((long)3 * NT + ti) * NLM;
  __syncthreads();
  const float pb2 = phib[half * 64 + c] * TWO_LOG2E;
  const float Qt = Qw[tg + 64][c];
  float a0 = 0.f, a1 = 0.f, a2 = 0.f, a3 = 0.f;
#pragma unroll
  for (int lc = 0; lc < 4; ++lc) {
    float v[16];
#pragma unroll
    for (int u = 0; u < 16; ++u) {
      const int l = lc * 16 + u;
      const float cl = TWO_LOG2E / (float)(l + 9);  // folded constant
      float y = (Qt - Qw[tg + 63 - l][c]) * cl + pb2;
      v[u] = rcp_fast(exp2_fast(y) + 1.f);
    }
#pragma unroll
    for (int u = 0; u < 16; ++u) {
      const int l = lc * 16 + u;
      a0 = fmaf(p0[l], v[u], a0);
      a1 = fmaf(p1[l], v[u], a1);
      a2 = fmaf(p2[l], v[u], a2);
      a3 = fmaf(p3[l], v[u], a3);
    }
  }
  const long base = half * 64 + c;
  eq[((long)(0 * 8 + b) * NT + ti) * NC + base] = fmaf(-2.f, a0, 1.f);
  eq[((long)(1 * 8 + b) * NT + ti) * NC + base] = fmaf(-2.f, a1, 1.f);
  eq[((long)(2 * 8 + b) * NT + ti) * NC + base] = fmaf(-2.f, a2, 1.f);
  eq[((long)(3 * 8 + b) * NT + ti) * NC + base] = fmaf(-2.f, a3, 1.f);
}

// K5a-data: qlocal = R @ e per (s,b,chunk) — tiled GEMM, 8t x 8c per lane.
__global__ __launch_bounds__(128) void k5a_data(const float* __restrict__ rt,
                                                float* __restrict__ eq) {
  __shared__ __align__(16) float rts[4096];    // [tp][t] 16 KB
  __shared__ __align__(16) float es[64][128];  // 32 KB
  const int sb = blockIdx.x;  // s*8+b
  const int s = sb >> 3;
  const int ch = blockIdx.y;
  const int tid = threadIdx.x;
  const float4* rsrc = (const float4*)(rt + ((long)s * NCH + ch) * 4096);
#pragma unroll
  for (int i = 0; i < 8; ++i) ((float4*)rts)[tid + 128 * i] = rsrc[tid + 128 * i];
  float* qb = eq + ((long)sb * NT + ch * 64) * NC;
  const float4* esrc = (const float4*)qb;
#pragma unroll
  for (int i = 0; i < 16; ++i) ((float4*)es)[tid + 128 * i] = esrc[tid + 128 * i];
  __syncthreads();
  const int t0 = (tid >> 4) * 8;  // 8 t-tiles
  const int c0 = (tid & 15) * 8;  // 16 c-tiles
  float acc[8][8];
#pragma unroll
  for (int i = 0; i < 8; ++i)
#pragma unroll
    for (int k = 0; k < 8; ++k) acc[i][k] = 0.f;
  for (int tp = 0; tp < 64; ++tp) {
    if (tp <= t0 + 7) {  // R is lower-triangular
      float4 r0 = *(const float4*)&rts[tp * 64 + t0];
      float4 r1 = *(const float4*)&rts[tp * 64 + t0 + 4];
      float4 e0 = *(const float4*)&es[tp][c0];
      float4 e1 = *(const float4*)&es[tp][c0 + 4];
      float rr[8] = {r0.x, r0.y, r0.z, r0.w, r1.x, r1.y, r1.z, r1.w};
      float ee[8] = {e0.x, e0.y, e0.z, e0.w, e1.x, e1.y, e1.z, e1.w};
#pragma unroll
      for (int i = 0; i < 8; ++i)
#pragma unroll
        for (int k = 0; k < 8; ++k) acc[i][k] = fmaf(rr[i], ee[k], acc[i][k]);
    }
  }
#pragma unroll
  for (int i = 0; i < 8; ++i) {
    float4* dst = (float4*)(qb + (t0 + i) * NC + c0);
    dst[0] = make_float4(acc[i][0], acc[i][1], acc[i][2], acc[i][3]);
    dst[1] = make_float4(acc[i][4], acc[i][5], acc[i][6], acc[i][7]);
  }
}

// K5b v2 (R13): cross-chunk combine; cr chunk staged once per block through
// padded LDS (stride 65 => conflict-free), double-buffered across chunks;
// 4 waves per block, 4 channels per wave. History h broadcast via
// v_readlane. Blocks 0..255 = q-scan; blocks 256..259 = k-scan.
__global__ __launch_bounds__(256) void k5b_scan(const float* __restrict__ ctT,
                                                const float* __restrict__ klocal,
                                                float* __restrict__ eq,
                                                float* __restrict__ kout) {
  __shared__ float crs[2][64 * 65];  // 32.5 KB, padded stride 65
  const int tid = threadIdx.x;
  const int t = tid & 63;
  const int w = tid >> 6;
  const int bid = blockIdx.x;
  const bool isq = bid < 256;
  const int s = isq ? ((bid & 7) >> 1) : (bid - 256);
  const float* ctTs = ctT + (long)s * NCH * 4096;

  // staging geometry: thread -> (row sr, 16-float quarter sq); 16 floats each
  const int sr = tid >> 2;
  const int sq = (tid & 3) * 16;
  float4 stg0, stg1, stg2, stg3;

#define K5B_STAGE_LOAD(CH)                                                    \
  {                                                                           \
    const float4* p_ = (const float4*)(ctTs + (CH)*4096 + sr * 64 + sq);      \
    stg0 = p_[0]; stg1 = p_[1]; stg2 = p_[2]; stg3 = p_[3];                   \
  }
#define K5B_STAGE_WRITE(BUF)                                                  \
  {                                                                           \
    float* d_ = &crs[BUF][sr * 65 + sq];                                      \
    d_[0] = stg0.x;  d_[1] = stg0.y;  d_[2] = stg0.z;  d_[3] = stg0.w;        \
    d_[4] = stg1.x;  d_[5] = stg1.y;  d_[6] = stg1.z;  d_[7] = stg1.w;        \
    d_[8] = stg2.x;  d_[9] = stg2.y;  d_[10] = stg2.z; d_[11] = stg2.w;       \
    d_[12] = stg3.x; d_[13] = stg3.y; d_[14] = stg3.z; d_[15] = stg3.w;       \
  }

  // q-branch mapping: per (s,b) 8 blocks x 4 waves x 4 channels = 128 ch
  const int g = bid >> 3;
  const int bb = g & 7, pp = g >> 3;  // pp 0..3 (q-blocks)
  const int hp = bid & 1;
  const int c0 = ((((pp << 1) | hp) << 2) | w) * 4;  // slice*4, slice 0..31
  const int sb = s * 8 + bb;
  float* eqb = eq + (long)sb * NT * NC + c0;

  float hv0 = 0.f, hv1 = 0.f, hv2 = 0.f, hv3 = 0.f;  // q history (per lane t)
  float hk = 0.f;                                    // k history

  K5B_STAGE_LOAD(0)
  K5B_STAGE_WRITE(0)
  __syncthreads();
#pragma unroll 1
  for (int ch = 0; ch < NCH; ++ch) {
    const int cur = ch & 1;
    if (ch + 1 < NCH) K5B_STAGE_LOAD(ch + 1)  // issue early; lands at write
    if (isq) {
      const float* cr = &crs[cur][t * 65];
      float4 ql = *(const float4*)(eqb + (long)(ch * 64 + t) * NC);
      float a0 = 0.f, a1 = 0.f, a2 = 0.f, a3 = 0.f;
#pragma unroll
      for (int j = 0; j < 64; ++j) {
        float cv = cr[j];
        a0 = fmaf(cv, readlane_f(hv0, 63 - j), a0);
        a1 = fmaf(cv, readlane_f(hv1, 63 - j), a1);
        a2 = fmaf(cv, readlane_f(hv2, 63 - j), a2);
        a3 = fmaf(cv, readlane_f(hv3, 63 - j), a3);
      }
      hv0 = a0 + ql.x; hv1 = a1 + ql.y; hv2 = a2 + ql.z; hv3 = a3 + ql.w;
      *(float4*)(eqb + (long)(ch * 64 + t) * NC) =
          make_float4(hv0, hv1, hv2, hv3);
    } else if (tid < 64) {
      const float* cr = &crs[cur][t * 65];
      float acc = klocal[((long)s * NCH + ch) * 64 + t];
#pragma unroll
      for (int j = 0; j < 64; ++j)
        acc = fmaf(cr[j], readlane_f(hk, 63 - j), acc);
      kout[s * NT + ch * 64 + t] = acc;
      hk = acc;
    }
    __syncthreads();  // all waves done READING crs[cur^1] (chunk ch-1)
    if (ch + 1 < NCH) K5B_STAGE_WRITE(cur ^ 1)
    __syncthreads();  // crs[cur^1] ready for chunk ch+1
  }
#undef K5B_STAGE_LOAD
#undef K5B_STAGE_WRITE
}

// K6 v3 (R26 == R25 resubmit; R25 died at container ACQUISITION, before
// any kernel code ran). REVERT to the R23 structure (measured 61.4us)
// after R24's tile rebalance regressed to 142.9us (VALUBusy 65->17%).
// Post-mortem: the LDS broadcasts were never the cost — the old tile's 8
// deep acc chains x 8 fma per weight load are what hid the ~200-300cy L2
// latency of the shared mixw stream; R24 cut that ILP 4x AND doubled the
// L2 requesters. Lesson: for a shared L2-resident B-matrix stream,
// per-load reuse + per-thread MLP dominate; occupancy is secondary.
// One same-direction tweak vs R23: kk chunked by 8 (8 weight loads issued
// ahead of the fma block) — doubles outstanding mixw loads per wave
// without touching reuse, block count, or LDS layout.
__global__ __launch_bounds__(256) void k6_mix(
    const float* __restrict__ q, const float* __restrict__ kout,
    const float* __restrict__ anchor, const float* __restrict__ mixw,
    const float* __restrict__ mixb, float* __restrict__ out) {
  __shared__ __align__(16) float rsdata[16][512];  // 32 KB
  const int b = blockIdx.x;
  const int t0 = blockIdx.y * 16;
  const int tid = threadIdx.x;
  for (int i = tid; i < 16 * 512; i += 256) {
    int r = i >> 9, sc = i & 511;
    int s = sc >> 7, c = sc & 127;
    int ti = t0 + r;
    float qv = q[((long)(s * 8 + b) * NT + ti) * NC + c];
    float kv = kout[s * NT + ti];
    float d1 = rcp_fast(kv + 16.f);
    rsdata[r][sc] = (qv + 16.f * anchor[sc]) * d1 * (kv * d1);
  }
  __syncthreads();
  const int co = tid & 127, hf = tid >> 7;
  const int r0 = hf * 8;
  float mb = mixb[co];
  float acc[8];
#pragma unroll
  for (int r = 0; r < 8; ++r) acc[r] = mb;
  for (int kk = 0; kk < 512; kk += 8) {
    float w0 = mixw[(kk + 0) * 128 + co];
    float w1 = mixw[(kk + 1) * 128 + co];
    float w2 = mixw[(kk + 2) * 128 + co];
    float w3 = mixw[(kk + 3) * 128 + co];
    float w4 = mixw[(kk + 4) * 128 + co];
    float w5 = mixw[(kk + 5) * 128 + co];
    float w6 = mixw[(kk + 6) * 128 + co];
    float w7 = mixw[(kk + 7) * 128 + co];
#pragma unroll
    for (int r = 0; r < 8; ++r) {
      float4 rv0 = *(const float4*)&rsdata[r0 + r][kk];
      float4 rv1 = *(const float4*)&rsdata[r0 + r][kk + 4];
      acc[r] = fmaf(rv0.x, w0, acc[r]);
      acc[r] = fmaf(rv0.y, w1, acc[r]);
      acc[r] = fmaf(rv0.z, w2, acc[r]);
      acc[r] = fmaf(rv0.w, w3, acc[r]);
      acc[r] = fmaf(rv1.x, w4, acc[r]);
      acc[r] = fmaf(rv1.y, w5, acc[r]);
      acc[r] = fmaf(rv1.z, w6, acc[r]);
      acc[r] = fmaf(rv1.w, w7, acc[r]);
    }
  }
#pragma unroll
  for (int r = 0; r < 8; ++r)
    out[((long)b * NT + t0 + r0 + r) * NC + co] = acc[r];
}

extern "C" void kernel_launch(void* const* d_in, const int* in_sizes, int n_in,
                              void* d_out, int out_size, void* d_ws, size_t ws_size,
                              hipStream_t stream) {
  const float* x = (const float*)d_in[0];
  const float* W = (const float*)d_in[1];
  const float* bias = (const float*)d_in[2];
  const float* phiw = (const float*)d_in[3];
  const float* phib = (const float*)d_in[4];
  const float* anchor = (const float*)d_in[5];
  const float* logw = (const float*)d_in[6];
  const float* mixw = (const float*)d_in[7];
  const float* mixb = (const float*)d_in[8];
  float* out = (float*)d_out;

  float* ws = (float*)d_ws;
  float* Q = ws;                                     // 8*2049*128 = 2,098,176
  float* pi = Q + (long)NB * QROWS * NC;             // 4*2048*64  =   524,288
  float* eq = pi + (long)NS * NT * NLM;              // 32*2048*128= 8,388,608
  float* coefTT = eq + (long)NS * NB * NT * NC;      //               524,288
  float* rtb = coefTT + (long)NS * NCH * 4096;       //               524,288
  float* klocal = rtb + (long)NS * NCH * 4096;       //                 8,192
  float* kout = klocal + (long)NS * NCH * 64;        //                 8,192
  float* logZt = kout + (long)NS * NT;               //                 8,196
  float* S2 = logZt + (long)NS * QROWS;              //                32,768

  hipLaunchKernelGGL(k1_uv, dim3(NB * NT / 16), dim3(256), 0, stream, x, W, bias, phiw, Q);
  hipLaunchKernelGGL(k23_sums_logz, dim3(260), dim3(128), 0, stream, Q, S2, logw, logZt);
  hipLaunchKernelGGL(kb_basis_fix, dim3(384), dim3(128), 0, stream, logw, logZt, pi, rtb, coefTT, klocal, Q, S2);
  hipLaunchKernelGGL(k4_e, dim3(NB, NT / 4, 2), dim3(256), 0, stream, Q, pi, phib, eq);
  hipLaunchKernelGGL(k5a_data, dim3(NS * NB, NCH), dim3(128), 0, stream, rtb, eq);
  hipLaunchKernelGGL(k5b_scan, dim3(260), dim3(256), 0, stream, coefTT, klocal, eq, kout);
  hipLaunchKernelGGL(k6_mix, dim3(NB, NT / 16), dim3(256), 0, stream, eq, kout, anchor, mixw, mixb, out);
}

// Round 15
// 343.707 us; speedup vs baseline: 1.2081x; 1.0133x over previous
//
#include <hip/hip_runtime.h>
#include <math.h>

// Problem constants
#define NB 8
#define NT 2048
#define NC 128
#define NLM 64
#define NS 4
#define QROWS 2049
#define NCH 32  // 2048 / 64 chunks

#define TWO_LOG2E 2.885390081777927f
#define LOG2E_F 1.4426950408889634f

__device__ __forceinline__ float rcp_fast(float x) {
  return __builtin_amdgcn_rcpf(x);
}

__device__ __forceinline__ float readlane_f(float v, int lane) {
  return __int_as_float(__builtin_amdgcn_readlane(__float_as_int(v), lane));
}

// Raw v_exp_f32 (2^x). Safe here: |y| bounded ~12, far from denorm/inf
// edges where the libm denorm-guard sequence matters.
__device__ __forceinline__ float exp2_fast(float x) {
  float r;
  asm("v_exp_f32 %0, %1" : "=v"(r) : "v"(x));
  return r;
}

// HW trig in revolutions. v_sin/v_cos REQUIRE the input reduced to [0,1)
// via v_fract (ISA: "reduce with v_fract_f32 first") — R14 fed unreduced
// values (|rev|<2) and got O(1) errors. Both are period-1 in revolutions,
// so fract is mathematically exact here.
__device__ __forceinline__ float fract_fast(float x) {
  float r;
  asm("v_fract_f32 %0, %1" : "=v"(r) : "v"(x));
  return r;
}
__device__ __forceinline__ float sin_rev(float r) {
  float d;
  asm("v_sin_f32 %0, %1" : "=v"(d) : "v"(r));
  return d;
}
__device__ __forceinline__ float cos_rev(float r) {
  float d;
  asm("v_cos_f32 %0, %1" : "=v"(d) : "v"(r));
  return d;
}

// ---------------------------------------------------------------------------
// Tiled 64-step local linear scan (forward substitution); all indices
// compile-time so q[4][16] stays in VGPRs. (Used by k23's logZ branch.)
// ---------------------------------------------------------------------------
template <typename PF, typename DF>
__device__ __forceinline__ void tri_scan64(PF P, DF D, float q[4][16]) {
#pragma unroll
  for (int tau = 0; tau < 4; ++tau) {
    float acc[16];
#pragma unroll
    for (int i = 0; i < 16; ++i) acc[i] = D(tau * 16 + i);
#pragma unroll
    for (int p = 0; p < 4; ++p) {
      if (p < tau) {
#pragma unroll
        for (int i = 0; i < 16; ++i) {
          const int t = tau * 16 + i;
#pragma unroll
          for (int i2 = 0; i2 < 16; ++i2) {
            acc[i] = fmaf(P(t, t - (p * 16 + i2) - 1), q[p][i2], acc[i]);
          }
        }
      }
    }
#pragma unroll
    for (int i = 0; i < 16; ++i) {
      const int t = tau * 16 + i;
#pragma unroll
      for (int i2 = 0; i2 < 16; ++i2) {
        if (i2 < i) acc[i] = fmaf(P(t, i - i2 - 1), q[tau][i2], acc[i]);
      }
      q[tau][i] = acc[i];
    }
  }
}

// K1 v3 (R27): R22's occupancy structure + HW trig with PROPER fract
// reduction (the R14 failure is now diagnosed: v_sin/v_cos need [0,1)
// input — "reduce with v_fract_f32 first"; R14 skipped the fract).
// sincosf (libm, ~40-80 VALU each incl. Payne-Hanek) -> 1 mul + 1 fract
// + 2 trans per eval; ~400-800 instrs cut from k1's ~3400-instr stream.
__global__ __launch_bounds__(256) void k1_uv(
    const float* __restrict__ x, const float* __restrict__ W,
    const float* __restrict__ bias, const float* __restrict__ phiw,
    float* __restrict__ Q) {
  __shared__ __align__(16) float xs[16][128];  // 8 KB
  __shared__ float us[16][256];                // 16 KB
  const int tid = threadIdx.x;
  const int j = tid & 127;  // column
  const int h = tid >> 7;   // row-half: rows h*8 .. h*8+7
  const int r0 = h * 8;
  const int bt0 = blockIdx.x * 16;
  {
    // 16 rows x 128 cols = 512 float4; 256 threads -> 2 each
    const float4* x4 = (const float4*)(x + (long)bt0 * NC);
    ((float4*)xs)[tid] = x4[tid];
    ((float4*)xs)[tid + 256] = x4[tid + 256];
  }
  __syncthreads();
  float z[8];
  const float bj = bias[j];
#pragma unroll
  for (int r = 0; r < 8; ++r) z[r] = bj;
  for (int k = 0; k < 128; ++k) {
    float w = W[k * 128 + j];
#pragma unroll
    for (int r = 0; r < 8; ++r) z[r] = fmaf(xs[r0 + r][k], w, z[r]);
  }
  const float rs = 0.08838834764831845f;   // 1/sqrt(128)
  const float inv2pi = 0.15915494309189535f;  // 1/(2*pi)
#pragma unroll
  for (int r = 0; r < 8; ++r) {
    float rf = fract_fast(z[r] * inv2pi);  // revolutions, reduced to [0,1)
    us[r0 + r][j] = cos_rev(rf) * rs;
    us[r0 + r][128 + j] = sin_rev(rf) * rs;
  }
  __syncthreads();
  float a[8];
#pragma unroll
  for (int r = 0; r < 8; ++r) a[r] = 0.f;
  for (int k = 0; k < 256; ++k) {
    float w = phiw[k * 128 + j];
#pragma unroll
    for (int r = 0; r < 8; ++r) a[r] = fmaf(us[r0 + r][k], w, a[r]);
  }
#pragma unroll
  for (int r = 0; r < 8; ++r) {
    int bt = bt0 + r0 + r;
    int b = bt >> 11, t = bt & 2047;
    Q[(b * QROWS + t + 1) * NC + j] = a[r];
  }
}

// K23 merged: blocks 0..255 = k2a (per-chunk raw sums of V);
//             blocks 256..259 = k3ab (serial logZ chunk evolution, per s).
__global__ __launch_bounds__(128) void k23_sums_logz(
    const float* __restrict__ Q, float* __restrict__ S2,
    const float* __restrict__ logw, float* __restrict__ logZt) {
  __shared__ float4 part[4][32];
  __shared__ float wx[64];
  __shared__ float mTs[64][65];
  __shared__ float Zr[64];
  const int x = blockIdx.x;
  const int tid = threadIdx.x;
  if (x < 256) {
    const int b = x >> 5, ch = x & 31;
    const int g = tid >> 5, c4 = tid & 31;
    const float4* Q4 = (const float4*)(Q + (long)(b * QROWS + ch * 64 + 1) * NC);
    float4 acc = make_float4(0.f, 0.f, 0.f, 0.f);
#pragma unroll
    for (int i = 0; i < 16; ++i) {
      float4 v = Q4[(g * 16 + i) * 32 + c4];
      acc.x += v.x; acc.y += v.y; acc.z += v.z; acc.w += v.w;
    }
    part[g][c4] = acc;
    __syncthreads();
    if (g == 0) {
      float4 p0 = part[0][c4], p1 = part[1][c4], p2 = part[2][c4], p3 = part[3][c4];
      ((float4*)(S2 + (long)(b * NCH + ch) * NC))[c4] =
          make_float4(p0.x + p1.x + p2.x + p3.x, p0.y + p1.y + p2.y + p3.y,
                      p0.z + p1.z + p2.z + p3.z, p0.w + p1.w + p2.w + p3.w);
    }
  } else {
    const int s = x - 256;
    const int j = tid;
    if (j < 64) wx[j] = __expf(logw[s * NLM + j]);
    __syncthreads();
    if (j < 64) {
      float q[4][16];
      tri_scan64([&](int t, int l) { return wx[l]; },
                 [&](int t) { int l = t + j; return (l < 64) ? wx[l] : 0.f; }, q);
#pragma unroll
      for (int tau = 0; tau < 4; ++tau)
#pragma unroll
        for (int i = 0; i < 16; ++i) mTs[j][tau * 16 + i] = q[tau][i];
    }
    const int t = j;
    if (t < 64) Zr[t] = (t == 0) ? 1.f : 0.f;
    if (t == 0) logZt[s * QROWS] = 0.f;
    float off = 0.f;
    __syncthreads();
    for (int ch = 0; ch < NCH; ++ch) {
      float acc = 0.f, mx = 0.f;
      if (t < 64) {
#pragma unroll 8
        for (int jj = 0; jj < 64; ++jj) acc = fmaf(mTs[jj][t], Zr[jj], acc);
        logZt[s * QROWS + ch * 64 + 1 + t] = logf(acc) + off;
        mx = acc;
#pragma unroll
        for (int o = 32; o; o >>= 1) mx = fmaxf(mx, __shfl_xor(mx, o));
      }
      __syncthreads();
      if (t < 64) {
        Zr[63 - t] = acc / mx;
        off += logf(mx);
      }
      __syncthreads();
    }
  }
}

// KB merged: blocks 0..127 = k5a_basis; blocks 128..383 = k2c (prefix fixup).
// Phase 0 uses the logsumexp identity: pi[t][l] = exp(lw[l] + logZ[t-l]
// - logZ[t+1]). Solve is the statically-tiled q[4][16] left-looking blocked
// substitution (R13).
__global__ __launch_bounds__(128) void kb_basis_fix(
    const float* __restrict__ logw, const float* __restrict__ logZt,
    float* __restrict__ pig, float* __restrict__ rt, float* __restrict__ ctT,
    float* __restrict__ klocal, float* __restrict__ Q,
    const float* __restrict__ S2) {
  // sbuf: [0,4096) psd (pi [t][l]); [4096,8192) Pts (Pt [t][t']);
  //       [8192,16384) Dl ([t][u], u=0..127). After the scan, Rl (stride 65)
  //       aliases [0,8192).
  __shared__ __align__(16) float sbuf[16384];  // 64 KB
  __shared__ float lzs[128];  // LOG2E * logZ[ch*64-63+i], i=0..127
  __shared__ float lws[64];   // LOG2E * logw
  __shared__ float4 gsum[4][32];
  float* psd = sbuf;
  float* Pts = sbuf + 4096;
  float* Dl = sbuf + 8192;
  float* Rl = sbuf;  // stride 65, valid after scan barrier
  const int x = blockIdx.x;
  const int tid = threadIdx.x;
  if (x < 128) {
    const int s = x >> 5, ch = x & 31;
    {
      int idx = ch * 64 - 63 + tid;  // max ch*64+64 <= 2048, in bounds
      lzs[tid] = (idx >= 0) ? logZt[s * QROWS + idx] * LOG2E_F : -INFINITY;
      if (tid < 64) lws[tid] = logw[s * NLM + tid] * LOG2E_F;
    }
    __syncthreads();
    {
      const int l = tid & 63, wv = tid >> 6;
      const float lw2 = lws[l];
      for (int tt = wv; tt < 64; tt += 2) {
        // la2 - lzn2 <= 0 by construction (logZ[t+1] = logsumexp of row)
        float e2 = lw2 + lzs[tt + 63 - l] - lzs[tt + 64];
        float pv = __builtin_exp2f(e2);
        psd[tt * 64 + l] = pv;
        pig[((long)s * NT + ch * 64 + tt) * NLM + l] = pv;
      }
    }
    __syncthreads();
    // Pt[t][t'] = psd[t][t-t'-1] (t'<t) else 0  (32 elems/thread)
    for (int i = tid; i < 4096; i += 128) {
      int t = i >> 6, tp = i & 63;
      Pts[i] = (tp < t) ? psd[t * 64 + (t - tp - 1)] : 0.f;
    }
    // Dl[t][u]: u<64 identity col u; u>=64 history col j=u-64 (64 elems/thread)
    for (int i = tid; i < 8192; i += 128) {
      int t = i >> 7, u = i & 127;
      float d;
      if (u < 64) {
        d = (t == u) ? 1.f : 0.f;
      } else {
        int l = t + (u - 64);
        d = (l < 64) ? psd[t * 64 + l] : 0.f;
      }
      Dl[i] = d;
    }
    __syncthreads();
    // unified forward substitution — statically tiled q[4][16], left-looking
    float q[4][16];
    const float* Dcol = Dl + tid;
#pragma unroll
    for (int tau = 0; tau < 4; ++tau) {
      float acc[16];
#pragma unroll
      for (int i = 0; i < 16; ++i) acc[i] = Dcol[(tau * 16 + i) * 128];
      // full 16x16 blocks from previous tiles (float4 broadcast loads)
#pragma unroll
      for (int p = 0; p < 4; ++p) {
        if (p < tau) {
#pragma unroll
          for (int i = 0; i < 16; ++i) {
            const int tr = tau * 16 + i;
            float a = acc[i];
#pragma unroll
            for (int q4 = 0; q4 < 4; ++q4) {
              float4 p4 = *(const float4*)&Pts[tr * 64 + p * 16 + q4 * 4];
              a = fmaf(p4.x, q[p][4 * q4 + 0], a);
              a = fmaf(p4.y, q[p][4 * q4 + 1], a);
              a = fmaf(p4.z, q[p][4 * q4 + 2], a);
              a = fmaf(p4.w, q[p][4 * q4 + 3], a);
            }
            acc[i] = a;
          }
        }
      }
      // serial intra-tile triangle (scalar broadcast loads)
#pragma unroll
      for (int i = 0; i < 16; ++i) {
        const int tr = tau * 16 + i;
        float a = acc[i];
#pragma unroll
        for (int i2 = 0; i2 < 16; ++i2) {
          if (i2 < i) a = fmaf(Pts[tr * 64 + tau * 16 + i2], q[tau][i2], a);
        }
        q[tau][i] = a;
      }
    }
    __syncthreads();  // psd/Pts dead; Rl may now alias them
    if (tid < 64) {
      const int tp = tid;  // impulse column
      float* rrow = rt + (((long)s * NCH + ch) * 64 + tp) * 64;  // [tp][t]
#pragma unroll
      for (int t4 = 0; t4 < 16; ++t4)
        ((float4*)rrow)[t4] = make_float4(
            q[t4 >> 2][4 * (t4 & 3) + 0], q[t4 >> 2][4 * (t4 & 3) + 1],
            q[t4 >> 2][4 * (t4 & 3) + 2], q[t4 >> 2][4 * (t4 & 3) + 3]);
#pragma unroll
      for (int tt = 0; tt < 4; ++tt)
#pragma unroll
        for (int i = 0; i < 16; ++i) Rl[tp * 65 + tt * 16 + i] = q[tt][i];
    } else {
      const int j = tid - 64;  // history lookback j+1
      float* ctb = ctT + ((long)s * NCH + ch) * 4096;  // [t][j]
#pragma unroll
      for (int tt = 0; tt < 4; ++tt)
#pragma unroll
        for (int i = 0; i < 16; ++i) ctb[(tt * 16 + i) * 64 + j] = q[tt][i];
    }
    __syncthreads();
    if (tid < 64) {  // klocal[t] = sum_tp R[t][tp]
      float acc = 0.f;
#pragma unroll 8
      for (int tp = 0; tp < 64; ++tp) acc += Rl[tp * 65 + tid];
      klocal[((long)s * NCH + ch) * 64 + tid] = acc;
    }
  } else {
    const int y = x - 128;
    const int b = y >> 5, ch = y & 31;
    const int g = tid >> 5, c4 = tid & 31;
    if (ch == 0 && g == 0)
      ((float4*)(Q + (long)(b * QROWS) * NC))[c4] = make_float4(0.f, 0.f, 0.f, 0.f);
    float4 run = make_float4(0.f, 0.f, 0.f, 0.f);
    for (int i = 0; i < ch; ++i) {
      float4 v = ((const float4*)(S2 + (long)(b * NCH + i) * NC))[c4];
      run.x += v.x; run.y += v.y; run.z += v.z; run.w += v.w;
    }
    float4* Q4 = (float4*)(Q + (long)(b * QROWS + ch * 64 + 1) * NC);
    float4 vbuf[16];
#pragma unroll
    for (int i = 0; i < 16; ++i) vbuf[i] = Q4[(g * 16 + i) * 32 + c4];
    {
      float4 gs = make_float4(0.f, 0.f, 0.f, 0.f);
#pragma unroll
      for (int i = 0; i < 16; ++i) {
        gs.x += vbuf[i].x; gs.y += vbuf[i].y; gs.z += vbuf[i].z; gs.w += vbuf[i].w;
      }
      gsum[g][c4] = gs;
    }
    __syncthreads();
    for (int gp = 0; gp < 3; ++gp) {
      if (gp < g) {
        float4 v = gsum[gp][c4];
        run.x += v.x; run.y += v.y; run.z += v.z; run.w += v.w;
      }
    }
#pragma unroll
    for (int i = 0; i < 16; ++i) {
      run.x += vbuf[i].x; run.y += vbuf[i].y; run.z += vbuf[i].z; run.w += vbuf[i].w;
      Q4[(g * 16 + i) * 32 + c4] = run;
    }
  }
}

// K4 v6 (R23, measured): scalar-path weights confirmed — left top-5
// (<61.3us, was 63.5). readfirstlane-proven-uniform pi rows lower to
// s_load; weights arrive as the fma's SGPR operand, zero readlanes.
__global__ __launch_bounds__(256) void k4_e(
    const float* __restrict__ Q, const float* __restrict__ pi,
    const float* __restrict__ phib, float* __restrict__ eq) {
  __shared__ float Qw[68][64];  // 17 KB
  const int b = blockIdx.x;
  const int t0 = blockIdx.y * 4;
  const int half = blockIdx.z;
  const int tid = threadIdx.x;
  for (int i = tid; i < 68 * 64; i += 256) {
    int r = i >> 6, cc = i & 63;
    int tau = t0 - 63 + r;
    Qw[r][cc] = (tau >= 0) ? Q[(b * QROWS + tau) * NC + half * 64 + cc] : 0.f;
  }
  const int c = tid & 63, tg = tid >> 6;  // c == lane id; tg == t-row
  // ti is wave-uniform (tg = tid>>6); readfirstlane makes that provable so
  // the weight loads scalarize to s_load (SGPR operands, no readlanes).
  const int ti = __builtin_amdgcn_readfirstlane(t0 + tg);
  const float* p0 = pi + ((long)0 * NT + ti) * NLM;
  const float* p1 = pi + ((long)1 * NT + ti) * NLM;
  const float* p2 = pi + ((long)2 * NT + ti) * NLM;
  const float* p3 = pi + ((long)3 * NT + ti) * NLM;
  __syncthreads();
  const float pb2 = phib[half * 64 + c] * TWO_LOG2E;
  const float Qt = Qw[tg + 64][c];
  float a0 = 0.f, a1 = 0.f, a2 = 0.f, a3 = 0.f;
#pragma unroll
  for (int lc = 0; lc < 4; ++lc) {
    float v[16];
#pragma unroll
    for (int u = 0; u < 16; ++u) {
      const int l = lc * 16 + u;
      const float cl = TWO_LOG2E / (float)(l + 9);  // folded constant
      float y = (Qt - Qw[tg + 63 - l][c]) * cl + pb2;
      v[u] = rcp_fast(exp2_fast(y) + 1.f);
    }
#pragma unroll
    for (int u = 0; u < 16; ++u) {
      const int l = lc * 16 + u;
      a0 = fmaf(p0[l], v[u], a0);
      a1 = fmaf(p1[l], v[u], a1);
      a2 = fmaf(p2[l], v[u], a2);
      a3 = fmaf(p3[l], v[u], a3);
    }
  }
  const long base = half * 64 + c;
  eq[((long)(0 * 8 + b) * NT + ti) * NC + base] = fmaf(-2.f, a0, 1.f);
  eq[((long)(1 * 8 + b) * NT + ti) * NC + base] = fmaf(-2.f, a1, 1.f);
  eq[((long)(2 * 8 + b) * NT + ti) * NC + base] = fmaf(-2.f, a2, 1.f);
  eq[((long)(3 * 8 + b) * NT + ti) * NC + base] = fmaf(-2.f, a3, 1.f);
}

// K5a-data: qlocal = R @ e per (s,b,chunk) — tiled GEMM, 8t x 8c per lane.
__global__ __launch_bounds__(128) void k5a_data(const float* __restrict__ rt,
                                                float* __restrict__ eq) {
  __shared__ __align__(16) float rts[4096];    // [tp][t] 16 KB
  __shared__ __align__(16) float es[64][128];  // 32 KB
  const int sb = blockIdx.x;  // s*8+b
  const int s = sb >> 3;
  const int ch = blockIdx.y;
  const int tid = threadIdx.x;
  const float4* rsrc = (const float4*)(rt + ((long)s * NCH + ch) * 4096);
#pragma unroll
  for (int i = 0; i < 8; ++i) ((float4*)rts)[tid + 128 * i] = rsrc[tid + 128 * i];
  float* qb = eq + ((long)sb * NT + ch * 64) * NC;
  const float4* esrc = (const float4*)qb;
#pragma unroll
  for (int i = 0; i < 16; ++i) ((float4*)es)[tid + 128 * i] = esrc[tid + 128 * i];
  __syncthreads();
  const int t0 = (tid >> 4) * 8;  // 8 t-tiles
  const int c0 = (tid & 15) * 8;  // 16 c-tiles
  float acc[8][8];
#pragma unroll
  for (int i = 0; i < 8; ++i)
#pragma unroll
    for (int k = 0; k < 8; ++k) acc[i][k] = 0.f;
  for (int tp = 0; tp < 64; ++tp) {
    if (tp <= t0 + 7) {  // R is lower-triangular
      float4 r0 = *(const float4*)&rts[tp * 64 + t0];
      float4 r1 = *(const float4*)&rts[tp * 64 + t0 + 4];
      float4 e0 = *(const float4*)&es[tp][c0];
      float4 e1 = *(const float4*)&es[tp][c0 + 4];
      float rr[8] = {r0.x, r0.y, r0.z, r0.w, r1.x, r1.y, r1.z, r1.w};
      float ee[8] = {e0.x, e0.y, e0.z, e0.w, e1.x, e1.y, e1.z, e1.w};
#pragma unroll
      for (int i = 0; i < 8; ++i)
#pragma unroll
        for (int k = 0; k < 8; ++k) acc[i][k] = fmaf(rr[i], ee[k], acc[i][k]);
    }
  }
#pragma unroll
  for (int i = 0; i < 8; ++i) {
    float4* dst = (float4*)(qb + (t0 + i) * NC + c0);
    dst[0] = make_float4(acc[i][0], acc[i][1], acc[i][2], acc[i][3]);
    dst[1] = make_float4(acc[i][4], acc[i][5], acc[i][6], acc[i][7]);
  }
}

// K5b v2 (R13): cross-chunk combine; cr chunk staged once per block through
// padded LDS (stride 65 => conflict-free), double-buffered across chunks;
// 4 waves per block, 4 channels per wave. History h broadcast via
// v_readlane. Blocks 0..255 = q-scan; blocks 256..259 = k-scan.
__global__ __launch_bounds__(256) void k5b_scan(const float* __restrict__ ctT,
                                                const float* __restrict__ klocal,
                                                float* __restrict__ eq,
                                                float* __restrict__ kout) {
  __shared__ float crs[2][64 * 65];  // 32.5 KB, padded stride 65
  const int tid = threadIdx.x;
  const int t = tid & 63;
  const int w = tid >> 6;
  const int bid = blockIdx.x;
  const bool isq = bid < 256;
  const int s = isq ? ((bid & 7) >> 1) : (bid - 256);
  const float* ctTs = ctT + (long)s * NCH * 4096;

  // staging geometry: thread -> (row sr, 16-float quarter sq); 16 floats each
  const int sr = tid >> 2;
  const int sq = (tid & 3) * 16;
  float4 stg0, stg1, stg2, stg3;

#define K5B_STAGE_LOAD(CH)                                                    \
  {                                                                           \
    const float4* p_ = (const float4*)(ctTs + (CH)*4096 + sr * 64 + sq);      \
    stg0 = p_[0]; stg1 = p_[1]; stg2 = p_[2]; stg3 = p_[3];                   \
  }
#define K5B_STAGE_WRITE(BUF)                                                  \
  {                                                                           \
    float* d_ = &crs[BUF][sr * 65 + sq];                                      \
    d_[0] = stg0.x;  d_[1] = stg0.y;  d_[2] = stg0.z;  d_[3] = stg0.w;        \
    d_[4] = stg1.x;  d_[5] = stg1.y;  d_[6] = stg1.z;  d_[7] = stg1.w;        \
    d_[8] = stg2.x;  d_[9] = stg2.y;  d_[10] = stg2.z; d_[11] = stg2.w;       \
    d_[12] = stg3.x; d_[13] = stg3.y; d_[14] = stg3.z; d_[15] = stg3.w;       \
  }

  // q-branch mapping: per (s,b) 8 blocks x 4 waves x 4 channels = 128 ch
  const int g = bid >> 3;
  const int bb = g & 7, pp = g >> 3;  // pp 0..3 (q-blocks)
  const int hp = bid & 1;
  const int c0 = ((((pp << 1) | hp) << 2) | w) * 4;  // slice*4, slice 0..31
  const int sb = s * 8 + bb;
  float* eqb = eq + (long)sb * NT * NC + c0;

  float hv0 = 0.f, hv1 = 0.f, hv2 = 0.f, hv3 = 0.f;  // q history (per lane t)
  float hk = 0.f;                                    // k history

  K5B_STAGE_LOAD(0)
  K5B_STAGE_WRITE(0)
  __syncthreads();
#pragma unroll 1
  for (int ch = 0; ch < NCH; ++ch) {
    const int cur = ch & 1;
    if (ch + 1 < NCH) K5B_STAGE_LOAD(ch + 1)  // issue early; lands at write
    if (isq) {
      const float* cr = &crs[cur][t * 65];
      float4 ql = *(const float4*)(eqb + (long)(ch * 64 + t) * NC);
      float a0 = 0.f, a1 = 0.f, a2 = 0.f, a3 = 0.f;
#pragma unroll
      for (int j = 0; j < 64; ++j) {
        float cv = cr[j];
        a0 = fmaf(cv, readlane_f(hv0, 63 - j), a0);
        a1 = fmaf(cv, readlane_f(hv1, 63 - j), a1);
        a2 = fmaf(cv, readlane_f(hv2, 63 - j), a2);
        a3 = fmaf(cv, readlane_f(hv3, 63 - j), a3);
      }
      hv0 = a0 + ql.x; hv1 = a1 + ql.y; hv2 = a2 + ql.z; hv3 = a3 + ql.w;
      *(float4*)(eqb + (long)(ch * 64 + t) * NC) =
          make_float4(hv0, hv1, hv2, hv3);
    } else if (tid < 64) {
      const float* cr = &crs[cur][t * 65];
      float acc = klocal[((long)s * NCH + ch) * 64 + t];
#pragma unroll
      for (int j = 0; j < 64; ++j)
        acc = fmaf(cr[j], readlane_f(hk, 63 - j), acc);
      kout[s * NT + ch * 64 + t] = acc;
      hk = acc;
    }
    __syncthreads();  // all waves done READING crs[cur^1] (chunk ch-1)
    if (ch + 1 < NCH) K5B_STAGE_WRITE(cur ^ 1)
    __syncthreads();  // crs[cur^1] ready for chunk ch+1
  }
#undef K5B_STAGE_LOAD
#undef K5B_STAGE_WRITE
}

// K6 v4 (R27): exact revert to the measured-best R23 structure (61.4us).
// R26's kk=8 load-ahead was neutral-to-slightly-negative (63.8, VGPR
// 48->52) — the compiler already schedules the loads ahead; the deeper
// unroll only cost registers. R24's tile rebalance (142.9us) and R26
// bracket this shape as the local optimum: 8 rows x 1 col per thread,
// 8 deep acc chains, 8 fma per mixw load, 16-row block, 32KB LDS.
__global__ __launch_bounds__(256) void k6_mix(
    const float* __restrict__ q, const float* __restrict__ kout,
    const float* __restrict__ anchor, const float* __restrict__ mixw,
    const float* __restrict__ mixb, float* __restrict__ out) {
  __shared__ __align__(16) float rsdata[16][512];  // 32 KB
  const int b = blockIdx.x;
  const int t0 = blockIdx.y * 16;
  const int tid = threadIdx.x;
  for (int i = tid; i < 16 * 512; i += 256) {
    int r = i >> 9, sc = i & 511;
    int s = sc >> 7, c = sc & 127;
    int ti = t0 + r;
    float qv = q[((long)(s * 8 + b) * NT + ti) * NC + c];
    float kv = kout[s * NT + ti];
    float d1 = rcp_fast(kv + 16.f);
    rsdata[r][sc] = (qv + 16.f * anchor[sc]) * d1 * (kv * d1);
  }
  __syncthreads();
  const int co = tid & 127, hf = tid >> 7;
  const int r0 = hf * 8;
  float mb = mixb[co];
  float acc[8];
#pragma unroll
  for (int r = 0; r < 8; ++r) acc[r] = mb;
  for (int kk = 0; kk < 512; kk += 4) {
    float wa = mixw[(kk + 0) * 128 + co];
    float wb = mixw[(kk + 1) * 128 + co];
    float wc = mixw[(kk + 2) * 128 + co];
    float wd = mixw[(kk + 3) * 128 + co];
#pragma unroll
    for (int r = 0; r < 8; ++r) {
      float4 rv = *(const float4*)&rsdata[r0 + r][kk];
      acc[r] = fmaf(rv.x, wa, acc[r]);
      acc[r] = fmaf(rv.y, wb, acc[r]);
      acc[r] = fmaf(rv.z, wc, acc[r]);
      acc[r] = fmaf(rv.w, wd, acc[r]);
    }
  }
#pragma unroll
  for (int r = 0; r < 8; ++r)
    out[((long)b * NT + t0 + r0 + r) * NC + co] = acc[r];
}

extern "C" void kernel_launch(void* const* d_in, const int* in_sizes, int n_in,
                              void* d_out, int out_size, void* d_ws, size_t ws_size,
                              hipStream_t stream) {
  const float* x = (const float*)d_in[0];
  const float* W = (const float*)d_in[1];
  const float* bias = (const float*)d_in[2];
  const float* phiw = (const float*)d_in[3];
  const float* phib = (const float*)d_in[4];
  const float* anchor = (const float*)d_in[5];
  const float* logw = (const float*)d_in[6];
  const float* mixw = (const float*)d_in[7];
  const float* mixb = (const float*)d_in[8];
  float* out = (float*)d_out;

  float* ws = (float*)d_ws;
  float* Q = ws;                                     // 8*2049*128 = 2,098,176
  float* pi = Q + (long)NB * QROWS * NC;             // 4*2048*64  =   524,288
  float* eq = pi + (long)NS * NT * NLM;              // 32*2048*128= 8,388,608
  float* coefTT = eq + (long)NS * NB * NT * NC;      //               524,288
  float* rtb = coefTT + (long)NS * NCH * 4096;       //               524,288
  float* klocal = rtb + (long)NS * NCH * 4096;       //                 8,192
  float* kout = klocal + (long)NS * NCH * 64;        //                 8,192
  float* logZt = kout + (long)NS * NT;               //                 8,196
  float* S2 = logZt + (long)NS * QROWS;              //                32,768

  hipLaunchKernelGGL(k1_uv, dim3(NB * NT / 16), dim3(256), 0, stream, x, W, bias, phiw, Q);
  hipLaunchKernelGGL(k23_sums_logz, dim3(260), dim3(128), 0, stream, Q, S2, logw, logZt);
  hipLaunchKernelGGL(kb_basis_fix, dim3(384), dim3(128), 0, stream, logw, logZt, pi, rtb, coefTT, klocal, Q, S2);
  hipLaunchKernelGGL(k4_e, dim3(NB, NT / 4, 2), dim3(256), 0, stream, Q, pi, phib, eq);
  hipLaunchKernelGGL(k5a_data, dim3(NS * NB, NCH), dim3(128), 0, stream, rtb, eq);
  hipLaunchKernelGGL(k5b_scan, dim3(260), dim3(256), 0, stream, coefTT, klocal, eq, kout);
  hipLaunchKernelGGL(k6_mix, dim3(NB, NT / 16), dim3(256), 0, stream, eq, kout, anchor, mixw, mixb, out);
}

// Round 16
// 343.390 us; speedup vs baseline: 1.2092x; 1.0009x over previous
//
#include <hip/hip_runtime.h>
#include <math.h>

// Problem constants
#define NB 8
#define NT 2048
#define NC 128
#define NLM 64
#define NS 4
#define QROWS 2049
#define NCH 32  // 2048 / 64 chunks

#define TWO_LOG2E 2.885390081777927f
#define LOG2E_F 1.4426950408889634f

__device__ __forceinline__ float rcp_fast(float x) {
  return __builtin_amdgcn_rcpf(x);
}

__device__ __forceinline__ float readlane_f(float v, int lane) {
  return __int_as_float(__builtin_amdgcn_readlane(__float_as_int(v), lane));
}

// Raw v_exp_f32 (2^x). Safe here: |y| bounded ~12, far from denorm/inf
// edges where the libm denorm-guard sequence matters.
__device__ __forceinline__ float exp2_fast(float x) {
  float r;
  asm("v_exp_f32 %0, %1" : "=v"(r) : "v"(x));
  return r;
}

// HW trig in revolutions with REQUIRED v_fract reduction (R27, verified:
// absmax unchanged vs libm).
__device__ __forceinline__ float fract_fast(float x) {
  float r;
  asm("v_fract_f32 %0, %1" : "=v"(r) : "v"(x));
  return r;
}
__device__ __forceinline__ float sin_rev(float r) {
  float d;
  asm("v_sin_f32 %0, %1" : "=v"(d) : "v"(r));
  return d;
}
__device__ __forceinline__ float cos_rev(float r) {
  float d;
  asm("v_cos_f32 %0, %1" : "=v"(d) : "v"(r));
  return d;
}

// ---------------------------------------------------------------------------
// Tiled 64-step local linear scan (forward substitution); all indices
// compile-time so q[4][16] stays in VGPRs. (Used by k23's logZ branch.)
// ---------------------------------------------------------------------------
template <typename PF, typename DF>
__device__ __forceinline__ void tri_scan64(PF P, DF D, float q[4][16]) {
#pragma unroll
  for (int tau = 0; tau < 4; ++tau) {
    float acc[16];
#pragma unroll
    for (int i = 0; i < 16; ++i) acc[i] = D(tau * 16 + i);
#pragma unroll
    for (int p = 0; p < 4; ++p) {
      if (p < tau) {
#pragma unroll
        for (int i = 0; i < 16; ++i) {
          const int t = tau * 16 + i;
#pragma unroll
          for (int i2 = 0; i2 < 16; ++i2) {
            acc[i] = fmaf(P(t, t - (p * 16 + i2) - 1), q[p][i2], acc[i]);
          }
        }
      }
    }
#pragma unroll
    for (int i = 0; i < 16; ++i) {
      const int t = tau * 16 + i;
#pragma unroll
      for (int i2 = 0; i2 < 16; ++i2) {
        if (i2 < i) acc[i] = fmaf(P(t, i - i2 - 1), q[tau][i2], acc[i]);
      }
      q[tau][i] = acc[i];
    }
  }
}

// K1 v3 (R27, measured): R22 structure + fract-reduced HW trig. Passed at
// absmax 4.9e-4; contributed ~-4.6us to total.
__global__ __launch_bounds__(256) void k1_uv(
    const float* __restrict__ x, const float* __restrict__ W,
    const float* __restrict__ bias, const float* __restrict__ phiw,
    float* __restrict__ Q) {
  __shared__ __align__(16) float xs[16][128];  // 8 KB
  __shared__ float us[16][256];                // 16 KB
  const int tid = threadIdx.x;
  const int j = tid & 127;  // column
  const int h = tid >> 7;   // row-half: rows h*8 .. h*8+7
  const int r0 = h * 8;
  const int bt0 = blockIdx.x * 16;
  {
    // 16 rows x 128 cols = 512 float4; 256 threads -> 2 each
    const float4* x4 = (const float4*)(x + (long)bt0 * NC);
    ((float4*)xs)[tid] = x4[tid];
    ((float4*)xs)[tid + 256] = x4[tid + 256];
  }
  __syncthreads();
  float z[8];
  const float bj = bias[j];
#pragma unroll
  for (int r = 0; r < 8; ++r) z[r] = bj;
  for (int k = 0; k < 128; ++k) {
    float w = W[k * 128 + j];
#pragma unroll
    for (int r = 0; r < 8; ++r) z[r] = fmaf(xs[r0 + r][k], w, z[r]);
  }
  const float rs = 0.08838834764831845f;   // 1/sqrt(128)
  const float inv2pi = 0.15915494309189535f;  // 1/(2*pi)
#pragma unroll
  for (int r = 0; r < 8; ++r) {
    float rf = fract_fast(z[r] * inv2pi);  // revolutions, reduced to [0,1)
    us[r0 + r][j] = cos_rev(rf) * rs;
    us[r0 + r][128 + j] = sin_rev(rf) * rs;
  }
  __syncthreads();
  float a[8];
#pragma unroll
  for (int r = 0; r < 8; ++r) a[r] = 0.f;
  for (int k = 0; k < 256; ++k) {
    float w = phiw[k * 128 + j];
#pragma unroll
    for (int r = 0; r < 8; ++r) a[r] = fmaf(us[r0 + r][k], w, a[r]);
  }
#pragma unroll
  for (int r = 0; r < 8; ++r) {
    int bt = bt0 + r0 + r;
    int b = bt >> 11, t = bt & 2047;
    Q[(b * QROWS + t + 1) * NC + j] = a[r];
  }
}

// K23 merged: blocks 0..255 = k2a (per-chunk raw sums of V);
//             blocks 256..259 = k3ab (serial logZ chunk evolution, per s).
__global__ __launch_bounds__(128) void k23_sums_logz(
    const float* __restrict__ Q, float* __restrict__ S2,
    const float* __restrict__ logw, float* __restrict__ logZt) {
  __shared__ float4 part[4][32];
  __shared__ float wx[64];
  __shared__ float mTs[64][65];
  __shared__ float Zr[64];
  const int x = blockIdx.x;
  const int tid = threadIdx.x;
  if (x < 256) {
    const int b = x >> 5, ch = x & 31;
    const int g = tid >> 5, c4 = tid & 31;
    const float4* Q4 = (const float4*)(Q + (long)(b * QROWS + ch * 64 + 1) * NC);
    float4 acc = make_float4(0.f, 0.f, 0.f, 0.f);
#pragma unroll
    for (int i = 0; i < 16; ++i) {
      float4 v = Q4[(g * 16 + i) * 32 + c4];
      acc.x += v.x; acc.y += v.y; acc.z += v.z; acc.w += v.w;
    }
    part[g][c4] = acc;
    __syncthreads();
    if (g == 0) {
      float4 p0 = part[0][c4], p1 = part[1][c4], p2 = part[2][c4], p3 = part[3][c4];
      ((float4*)(S2 + (long)(b * NCH + ch) * NC))[c4] =
          make_float4(p0.x + p1.x + p2.x + p3.x, p0.y + p1.y + p2.y + p3.y,
                      p0.z + p1.z + p2.z + p3.z, p0.w + p1.w + p2.w + p3.w);
    }
  } else {
    const int s = x - 256;
    const int j = tid;
    if (j < 64) wx[j] = __expf(logw[s * NLM + j]);
    __syncthreads();
    if (j < 64) {
      float q[4][16];
      tri_scan64([&](int t, int l) { return wx[l]; },
                 [&](int t) { int l = t + j; return (l < 64) ? wx[l] : 0.f; }, q);
#pragma unroll
      for (int tau = 0; tau < 4; ++tau)
#pragma unroll
        for (int i = 0; i < 16; ++i) mTs[j][tau * 16 + i] = q[tau][i];
    }
    const int t = j;
    if (t < 64) Zr[t] = (t == 0) ? 1.f : 0.f;
    if (t == 0) logZt[s * QROWS] = 0.f;
    float off = 0.f;
    __syncthreads();
    for (int ch = 0; ch < NCH; ++ch) {
      float acc = 0.f, mx = 0.f;
      if (t < 64) {
#pragma unroll 8
        for (int jj = 0; jj < 64; ++jj) acc = fmaf(mTs[jj][t], Zr[jj], acc);
        logZt[s * QROWS + ch * 64 + 1 + t] = logf(acc) + off;
        mx = acc;
#pragma unroll
        for (int o = 32; o; o >>= 1) mx = fmaxf(mx, __shfl_xor(mx, o));
      }
      __syncthreads();
      if (t < 64) {
        Zr[63 - t] = acc / mx;
        off += logf(mx);
      }
      __syncthreads();
    }
  }
}

// KB merged: blocks 0..127 = k5a_basis; blocks 128..383 = k2c (prefix fixup).
// Phase 0 uses the logsumexp identity: pi[t][l] = exp(lw[l] + logZ[t-l]
// - logZ[t+1]). Solve is the statically-tiled q[4][16] left-looking blocked
// substitution (R13).
__global__ __launch_bounds__(128) void kb_basis_fix(
    const float* __restrict__ logw, const float* __restrict__ logZt,
    float* __restrict__ pig, float* __restrict__ rt, float* __restrict__ ctT,
    float* __restrict__ klocal, float* __restrict__ Q,
    const float* __restrict__ S2) {
  // sbuf: [0,4096) psd (pi [t][l]); [4096,8192) Pts (Pt [t][t']);
  //       [8192,16384) Dl ([t][u], u=0..127). After the scan, Rl (stride 65)
  //       aliases [0,8192).
  __shared__ __align__(16) float sbuf[16384];  // 64 KB
  __shared__ float lzs[128];  // LOG2E * logZ[ch*64-63+i], i=0..127
  __shared__ float lws[64];   // LOG2E * logw
  __shared__ float4 gsum[4][32];
  float* psd = sbuf;
  float* Pts = sbuf + 4096;
  float* Dl = sbuf + 8192;
  float* Rl = sbuf;  // stride 65, valid after scan barrier
  const int x = blockIdx.x;
  const int tid = threadIdx.x;
  if (x < 128) {
    const int s = x >> 5, ch = x & 31;
    {
      int idx = ch * 64 - 63 + tid;  // max ch*64+64 <= 2048, in bounds
      lzs[tid] = (idx >= 0) ? logZt[s * QROWS + idx] * LOG2E_F : -INFINITY;
      if (tid < 64) lws[tid] = logw[s * NLM + tid] * LOG2E_F;
    }
    __syncthreads();
    {
      const int l = tid & 63, wv = tid >> 6;
      const float lw2 = lws[l];
      for (int tt = wv; tt < 64; tt += 2) {
        // la2 - lzn2 <= 0 by construction (logZ[t+1] = logsumexp of row)
        float e2 = lw2 + lzs[tt + 63 - l] - lzs[tt + 64];
        float pv = __builtin_exp2f(e2);
        psd[tt * 64 + l] = pv;
        pig[((long)s * NT + ch * 64 + tt) * NLM + l] = pv;
      }
    }
    __syncthreads();
    // Pt[t][t'] = psd[t][t-t'-1] (t'<t) else 0  (32 elems/thread)
    for (int i = tid; i < 4096; i += 128) {
      int t = i >> 6, tp = i & 63;
      Pts[i] = (tp < t) ? psd[t * 64 + (t - tp - 1)] : 0.f;
    }
    // Dl[t][u]: u<64 identity col u; u>=64 history col j=u-64 (64 elems/thread)
    for (int i = tid; i < 8192; i += 128) {
      int t = i >> 7, u = i & 127;
      float d;
      if (u < 64) {
        d = (t == u) ? 1.f : 0.f;
      } else {
        int l = t + (u - 64);
        d = (l < 64) ? psd[t * 64 + l] : 0.f;
      }
      Dl[i] = d;
    }
    __syncthreads();
    // unified forward substitution — statically tiled q[4][16], left-looking
    float q[4][16];
    const float* Dcol = Dl + tid;
#pragma unroll
    for (int tau = 0; tau < 4; ++tau) {
      float acc[16];
#pragma unroll
      for (int i = 0; i < 16; ++i) acc[i] = Dcol[(tau * 16 + i) * 128];
      // full 16x16 blocks from previous tiles (float4 broadcast loads)
#pragma unroll
      for (int p = 0; p < 4; ++p) {
        if (p < tau) {
#pragma unroll
          for (int i = 0; i < 16; ++i) {
            const int tr = tau * 16 + i;
            float a = acc[i];
#pragma unroll
            for (int q4 = 0; q4 < 4; ++q4) {
              float4 p4 = *(const float4*)&Pts[tr * 64 + p * 16 + q4 * 4];
              a = fmaf(p4.x, q[p][4 * q4 + 0], a);
              a = fmaf(p4.y, q[p][4 * q4 + 1], a);
              a = fmaf(p4.z, q[p][4 * q4 + 2], a);
              a = fmaf(p4.w, q[p][4 * q4 + 3], a);
            }
            acc[i] = a;
          }
        }
      }
      // serial intra-tile triangle (scalar broadcast loads)
#pragma unroll
      for (int i = 0; i < 16; ++i) {
        const int tr = tau * 16 + i;
        float a = acc[i];
#pragma unroll
        for (int i2 = 0; i2 < 16; ++i2) {
          if (i2 < i) a = fmaf(Pts[tr * 64 + tau * 16 + i2], q[tau][i2], a);
        }
        q[tau][i] = a;
      }
    }
    __syncthreads();  // psd/Pts dead; Rl may now alias them
    if (tid < 64) {
      const int tp = tid;  // impulse column
      float* rrow = rt + (((long)s * NCH + ch) * 64 + tp) * 64;  // [tp][t]
#pragma unroll
      for (int t4 = 0; t4 < 16; ++t4)
        ((float4*)rrow)[t4] = make_float4(
            q[t4 >> 2][4 * (t4 & 3) + 0], q[t4 >> 2][4 * (t4 & 3) + 1],
            q[t4 >> 2][4 * (t4 & 3) + 2], q[t4 >> 2][4 * (t4 & 3) + 3]);
#pragma unroll
      for (int tt = 0; tt < 4; ++tt)
#pragma unroll
        for (int i = 0; i < 16; ++i) Rl[tp * 65 + tt * 16 + i] = q[tt][i];
    } else {
      const int j = tid - 64;  // history lookback j+1
      float* ctb = ctT + ((long)s * NCH + ch) * 4096;  // [t][j]
#pragma unroll
      for (int tt = 0; tt < 4; ++tt)
#pragma unroll
        for (int i = 0; i < 16; ++i) ctb[(tt * 16 + i) * 64 + j] = q[tt][i];
    }
    __syncthreads();
    if (tid < 64) {  // klocal[t] = sum_tp R[t][tp]
      float acc = 0.f;
#pragma unroll 8
      for (int tp = 0; tp < 64; ++tp) acc += Rl[tp * 65 + tid];
      klocal[((long)s * NCH + ch) * 64 + tid] = acc;
    }
  } else {
    const int y = x - 128;
    const int b = y >> 5, ch = y & 31;
    const int g = tid >> 5, c4 = tid & 31;
    if (ch == 0 && g == 0)
      ((float4*)(Q + (long)(b * QROWS) * NC))[c4] = make_float4(0.f, 0.f, 0.f, 0.f);
    float4 run = make_float4(0.f, 0.f, 0.f, 0.f);
    for (int i = 0; i < ch; ++i) {
      float4 v = ((const float4*)(S2 + (long)(b * NCH + i) * NC))[c4];
      run.x += v.x; run.y += v.y; run.z += v.z; run.w += v.w;
    }
    float4* Q4 = (float4*)(Q + (long)(b * QROWS + ch * 64 + 1) * NC);
    float4 vbuf[16];
#pragma unroll
    for (int i = 0; i < 16; ++i) vbuf[i] = Q4[(g * 16 + i) * 32 + c4];
    {
      float4 gs = make_float4(0.f, 0.f, 0.f, 0.f);
#pragma unroll
      for (int i = 0; i < 16; ++i) {
        gs.x += vbuf[i].x; gs.y += vbuf[i].y; gs.z += vbuf[i].z; gs.w += vbuf[i].w;
      }
      gsum[g][c4] = gs;
    }
    __syncthreads();
    for (int gp = 0; gp < 3; ++gp) {
      if (gp < g) {
        float4 v = gsum[gp][c4];
        run.x += v.x; run.y += v.y; run.z += v.z; run.w += v.w;
      }
    }
#pragma unroll
    for (int i = 0; i < 16; ++i) {
      run.x += vbuf[i].x; run.y += vbuf[i].y; run.z += vbuf[i].z; run.w += vbuf[i].w;
      Q4[(g * 16 + i) * 32 + c4] = run;
    }
  }
}

// K4 v6 (R23, measured): scalar-path weights confirmed — left top-5
// (<61.3us, was 63.5). readfirstlane-proven-uniform pi rows lower to
// s_load; weights arrive as the fma's SGPR operand, zero readlanes.
__global__ __launch_bounds__(256) void k4_e(
    const float* __restrict__ Q, const float* __restrict__ pi,
    const float* __restrict__ phib, float* __restrict__ eq) {
  __shared__ float Qw[68][64];  // 17 KB
  const int b = blockIdx.x;
  const int t0 = blockIdx.y * 4;
  const int half = blockIdx.z;
  const int tid = threadIdx.x;
  for (int i = tid; i < 68 * 64; i += 256) {
    int r = i >> 6, cc = i & 63;
    int tau = t0 - 63 + r;
    Qw[r][cc] = (tau >= 0) ? Q[(b * QROWS + tau) * NC + half * 64 + cc] : 0.f;
  }
  const int c = tid & 63, tg = tid >> 6;  // c == lane id; tg == t-row
  // ti is wave-uniform (tg = tid>>6); readfirstlane makes that provable so
  // the weight loads scalarize to s_load (SGPR operands, no readlanes).
  const int ti = __builtin_amdgcn_readfirstlane(t0 + tg);
  const float* p0 = pi + ((long)0 * NT + ti) * NLM;
  const float* p1 = pi + ((long)1 * NT + ti) * NLM;
  const float* p2 = pi + ((long)2 * NT + ti) * NLM;
  const float* p3 = pi + ((long)3 * NT + ti) * NLM;
  __syncthreads();
  const float pb2 = phib[half * 64 + c] * TWO_LOG2E;
  const float Qt = Qw[tg + 64][c];
  float a0 = 0.f, a1 = 0.f, a2 = 0.f, a3 = 0.f;
#pragma unroll
  for (int lc = 0; lc < 4; ++lc) {
    float v[16];
#pragma unroll
    for (int u = 0; u < 16; ++u) {
      const int l = lc * 16 + u;
      const float cl = TWO_LOG2E / (float)(l + 9);  // folded constant
      float y = (Qt - Qw[tg + 63 - l][c]) * cl + pb2;
      v[u] = rcp_fast(exp2_fast(y) + 1.f);
    }
#pragma unroll
    for (int u = 0; u < 16; ++u) {
      const int l = lc * 16 + u;
      a0 = fmaf(p0[l], v[u], a0);
      a1 = fmaf(p1[l], v[u], a1);
      a2 = fmaf(p2[l], v[u], a2);
      a3 = fmaf(p3[l], v[u], a3);
    }
  }
  const long base = half * 64 + c;
  eq[((long)(0 * 8 + b) * NT + ti) * NC + base] = fmaf(-2.f, a0, 1.f);
  eq[((long)(1 * 8 + b) * NT + ti) * NC + base] = fmaf(-2.f, a1, 1.f);
  eq[((long)(2 * 8 + b) * NT + ti) * NC + base] = fmaf(-2.f, a2, 1.f);
  eq[((long)(3 * 8 + b) * NT + ti) * NC + base] = fmaf(-2.f, a3, 1.f);
}

// K5a-data: qlocal = R @ e per (s,b,chunk) — tiled GEMM, 8t x 8c per lane.
__global__ __launch_bounds__(128) void k5a_data(const float* __restrict__ rt,
                                                float* __restrict__ eq) {
  __shared__ __align__(16) float rts[4096];    // [tp][t] 16 KB
  __shared__ __align__(16) float es[64][128];  // 32 KB
  const int sb = blockIdx.x;  // s*8+b
  const int s = sb >> 3;
  const int ch = blockIdx.y;
  const int tid = threadIdx.x;
  const float4* rsrc = (const float4*)(rt + ((long)s * NCH + ch) * 4096);
#pragma unroll
  for (int i = 0; i < 8; ++i) ((float4*)rts)[tid + 128 * i] = rsrc[tid + 128 * i];
  float* qb = eq + ((long)sb * NT + ch * 64) * NC;
  const float4* esrc = (const float4*)qb;
#pragma unroll
  for (int i = 0; i < 16; ++i) ((float4*)es)[tid + 128 * i] = esrc[tid + 128 * i];
  __syncthreads();
  const int t0 = (tid >> 4) * 8;  // 8 t-tiles
  const int c0 = (tid & 15) * 8;  // 16 c-tiles
  float acc[8][8];
#pragma unroll
  for (int i = 0; i < 8; ++i)
#pragma unroll
    for (int k = 0; k < 8; ++k) acc[i][k] = 0.f;
  for (int tp = 0; tp < 64; ++tp) {
    if (tp <= t0 + 7) {  // R is lower-triangular
      float4 r0 = *(const float4*)&rts[tp * 64 + t0];
      float4 r1 = *(const float4*)&rts[tp * 64 + t0 + 4];
      float4 e0 = *(const float4*)&es[tp][c0];
      float4 e1 = *(const float4*)&es[tp][c0 + 4];
      float rr[8] = {r0.x, r0.y, r0.z, r0.w, r1.x, r1.y, r1.z, r1.w};
      float ee[8] = {e0.x, e0.y, e0.z, e0.w, e1.x, e1.y, e1.z, e1.w};
#pragma unroll
      for (int i = 0; i < 8; ++i)
#pragma unroll
        for (int k = 0; k < 8; ++k) acc[i][k] = fmaf(rr[i], ee[k], acc[i][k]);
    }
  }
#pragma unroll
  for (int i = 0; i < 8; ++i) {
    float4* dst = (float4*)(qb + (t0 + i) * NC + c0);
    dst[0] = make_float4(acc[i][0], acc[i][1], acc[i][2], acc[i][3]);
    dst[1] = make_float4(acc[i][4], acc[i][5], acc[i][6], acc[i][7]);
  }
}

// K5b v2 (R13): cross-chunk combine; cr chunk staged once per block through
// padded LDS (stride 65 => conflict-free), double-buffered across chunks;
// 4 waves per block, 4 channels per wave. History h broadcast via
// v_readlane. Blocks 0..255 = q-scan; blocks 256..259 = k-scan.
__global__ __launch_bounds__(256) void k5b_scan(const float* __restrict__ ctT,
                                                const float* __restrict__ klocal,
                                                float* __restrict__ eq,
                                                float* __restrict__ kout) {
  __shared__ float crs[2][64 * 65];  // 32.5 KB, padded stride 65
  const int tid = threadIdx.x;
  const int t = tid & 63;
  const int w = tid >> 6;
  const int bid = blockIdx.x;
  const bool isq = bid < 256;
  const int s = isq ? ((bid & 7) >> 1) : (bid - 256);
  const float* ctTs = ctT + (long)s * NCH * 4096;

  // staging geometry: thread -> (row sr, 16-float quarter sq); 16 floats each
  const int sr = tid >> 2;
  const int sq = (tid & 3) * 16;
  float4 stg0, stg1, stg2, stg3;

#define K5B_STAGE_LOAD(CH)                                                    \
  {                                                                           \
    const float4* p_ = (const float4*)(ctTs + (CH)*4096 + sr * 64 + sq);      \
    stg0 = p_[0]; stg1 = p_[1]; stg2 = p_[2]; stg3 = p_[3];                   \
  }
#define K5B_STAGE_WRITE(BUF)                                                  \
  {                                                                           \
    float* d_ = &crs[BUF][sr * 65 + sq];                                      \
    d_[0] = stg0.x;  d_[1] = stg0.y;  d_[2] = stg0.z;  d_[3] = stg0.w;        \
    d_[4] = stg1.x;  d_[5] = stg1.y;  d_[6] = stg1.z;  d_[7] = stg1.w;        \
    d_[8] = stg2.x;  d_[9] = stg2.y;  d_[10] = stg2.z; d_[11] = stg2.w;       \
    d_[12] = stg3.x; d_[13] = stg3.y; d_[14] = stg3.z; d_[15] = stg3.w;       \
  }

  // q-branch mapping: per (s,b) 8 blocks x 4 waves x 4 channels = 128 ch
  const int g = bid >> 3;
  const int bb = g & 7, pp = g >> 3;  // pp 0..3 (q-blocks)
  const int hp = bid & 1;
  const int c0 = ((((pp << 1) | hp) << 2) | w) * 4;  // slice*4, slice 0..31
  const int sb = s * 8 + bb;
  float* eqb = eq + (long)sb * NT * NC + c0;

  float hv0 = 0.f, hv1 = 0.f, hv2 = 0.f, hv3 = 0.f;  // q history (per lane t)
  float hk = 0.f;                                    // k history

  K5B_STAGE_LOAD(0)
  K5B_STAGE_WRITE(0)
  __syncthreads();
#pragma unroll 1
  for (int ch = 0; ch < NCH; ++ch) {
    const int cur = ch & 1;
    if (ch + 1 < NCH) K5B_STAGE_LOAD(ch + 1)  // issue early; lands at write
    if (isq) {
      const float* cr = &crs[cur][t * 65];
      float4 ql = *(const float4*)(eqb + (long)(ch * 64 + t) * NC);
      float a0 = 0.f, a1 = 0.f, a2 = 0.f, a3 = 0.f;
#pragma unroll
      for (int j = 0; j < 64; ++j) {
        float cv = cr[j];
        a0 = fmaf(cv, readlane_f(hv0, 63 - j), a0);
        a1 = fmaf(cv, readlane_f(hv1, 63 - j), a1);
        a2 = fmaf(cv, readlane_f(hv2, 63 - j), a2);
        a3 = fmaf(cv, readlane_f(hv3, 63 - j), a3);
      }
      hv0 = a0 + ql.x; hv1 = a1 + ql.y; hv2 = a2 + ql.z; hv3 = a3 + ql.w;
      *(float4*)(eqb + (long)(ch * 64 + t) * NC) =
          make_float4(hv0, hv1, hv2, hv3);
    } else if (tid < 64) {
      const float* cr = &crs[cur][t * 65];
      float acc = klocal[((long)s * NCH + ch) * 64 + t];
#pragma unroll
      for (int j = 0; j < 64; ++j)
        acc = fmaf(cr[j], readlane_f(hk, 63 - j), acc);
      kout[s * NT + ch * 64 + t] = acc;
      hk = acc;
    }
    __syncthreads();  // all waves done READING crs[cur^1] (chunk ch-1)
    if (ch + 1 < NCH) K5B_STAGE_WRITE(cur ^ 1)
    __syncthreads();  // crs[cur^1] ready for chunk ch+1
  }
#undef K5B_STAGE_LOAD
#undef K5B_STAGE_WRITE
}

// K6 v5 (R28): split-K. R23/R26/R24 bracketed the tile shape (8 rows x 1
// col, 8 fma/load, 8 chains = local optimum) but not the parallelism:
// 63.5us @ Occupancy 31%, VALUBusy 67%, nothing saturated. Split K into
// two 256-wide halves via blockIdx.z: same winning tile shape, LDS
// 32->16KB, blocks/CU 4->8, waves/CU 16->32 — R24's occupancy WITHOUT its
// ILP sacrifice. z=0 writes partial+mixb to out; z=1 writes its partial
// into the DEAD Q workspace (unread after k4; 2098176 >= 2097152 floats).
// k7_add sums them (~5us). No atomics, no race.
__global__ __launch_bounds__(256) void k6_mix(
    const float* __restrict__ q, const float* __restrict__ kout,
    const float* __restrict__ anchor, const float* __restrict__ mixw,
    const float* __restrict__ mixb, float* __restrict__ out,
    float* __restrict__ part) {
  __shared__ __align__(16) float rsdata[16][256];  // 16 KB
  const int b = blockIdx.x;
  const int t0 = blockIdx.y * 16;
  const int z = blockIdx.z;   // K-half
  const int sc0 = z * 256;
  const int tid = threadIdx.x;
  for (int i = tid; i < 16 * 256; i += 256) {
    int r = i >> 8, scl = i & 255;
    int sc = sc0 + scl;
    int s = sc >> 7, c = sc & 127;
    int ti = t0 + r;
    float qv = q[((long)(s * 8 + b) * NT + ti) * NC + c];
    float kv = kout[s * NT + ti];
    float d1 = rcp_fast(kv + 16.f);
    rsdata[r][scl] = (qv + 16.f * anchor[sc]) * d1 * (kv * d1);
  }
  __syncthreads();
  const int co = tid & 127, hf = tid >> 7;
  const int r0 = hf * 8;
  const float init = (z == 0) ? mixb[co] : 0.f;
  float acc[8];
#pragma unroll
  for (int r = 0; r < 8; ++r) acc[r] = init;
  const float* mw = mixw + (long)sc0 * 128 + co;
  for (int kk = 0; kk < 256; kk += 4) {
    float wa = mw[(kk + 0) * 128];
    float wb = mw[(kk + 1) * 128];
    float wc = mw[(kk + 2) * 128];
    float wd = mw[(kk + 3) * 128];
#pragma unroll
    for (int r = 0; r < 8; ++r) {
      float4 rv = *(const float4*)&rsdata[r0 + r][kk];
      acc[r] = fmaf(rv.x, wa, acc[r]);
      acc[r] = fmaf(rv.y, wb, acc[r]);
      acc[r] = fmaf(rv.z, wc, acc[r]);
      acc[r] = fmaf(rv.w, wd, acc[r]);
    }
  }
  float* dst = (z == 0) ? out : part;
#pragma unroll
  for (int r = 0; r < 8; ++r)
    dst[((long)b * NT + t0 + r0 + r) * NC + co] = acc[r];
}

// K7: out += part (the z=1 K-half partial). 2,097,152 floats = 524,288
// float4; 2048 blocks x 256 threads x 1 float4.
__global__ __launch_bounds__(256) void k7_add(float* __restrict__ out,
                                              const float* __restrict__ part) {
  const long i = (long)blockIdx.x * 256 + threadIdx.x;
  float4 a = ((const float4*)out)[i];
  float4 p = ((const float4*)part)[i];
  a.x += p.x; a.y += p.y; a.z += p.z; a.w += p.w;
  ((float4*)out)[i] = a;
}

extern "C" void kernel_launch(void* const* d_in, const int* in_sizes, int n_in,
                              void* d_out, int out_size, void* d_ws, size_t ws_size,
                              hipStream_t stream) {
  const float* x = (const float*)d_in[0];
  const float* W = (const float*)d_in[1];
  const float* bias = (const float*)d_in[2];
  const float* phiw = (const float*)d_in[3];
  const float* phib = (const float*)d_in[4];
  const float* anchor = (const float*)d_in[5];
  const float* logw = (const float*)d_in[6];
  const float* mixw = (const float*)d_in[7];
  const float* mixb = (const float*)d_in[8];
  float* out = (float*)d_out;

  float* ws = (float*)d_ws;
  float* Q = ws;                                     // 8*2049*128 = 2,098,176
  float* pi = Q + (long)NB * QROWS * NC;             // 4*2048*64  =   524,288
  float* eq = pi + (long)NS * NT * NLM;              // 32*2048*128= 8,388,608
  float* coefTT = eq + (long)NS * NB * NT * NC;      //               524,288
  float* rtb = coefTT + (long)NS * NCH * 4096;       //               524,288
  float* klocal = rtb + (long)NS * NCH * 4096;       //                 8,192
  float* kout = klocal + (long)NS * NCH * 64;        //                 8,192
  float* logZt = kout + (long)NS * NT;               //                 8,196
  float* S2 = logZt + (long)NS * QROWS;              //                32,768

  hipLaunchKernelGGL(k1_uv, dim3(NB * NT / 16), dim3(256), 0, stream, x, W, bias, phiw, Q);
  hipLaunchKernelGGL(k23_sums_logz, dim3(260), dim3(128), 0, stream, Q, S2, logw, logZt);
  hipLaunchKernelGGL(kb_basis_fix, dim3(384), dim3(128), 0, stream, logw, logZt, pi, rtb, coefTT, klocal, Q, S2);
  hipLaunchKernelGGL(k4_e, dim3(NB, NT / 4, 2), dim3(256), 0, stream, Q, pi, phib, eq);
  hipLaunchKernelGGL(k5a_data, dim3(NS * NB, NCH), dim3(128), 0, stream, rtb, eq);
  hipLaunchKernelGGL(k5b_scan, dim3(260), dim3(256), 0, stream, coefTT, klocal, eq, kout);
  // Q is dead after k4 — reuse it as the z=1 partial buffer for k6.
  hipLaunchKernelGGL(k6_mix, dim3(NB, NT / 16, 2), dim3(256), 0, stream, eq, kout, anchor, mixw, mixb, out, Q);
  hipLaunchKernelGGL(k7_add, dim3(2048), dim3(256), 0, stream, out, Q);
}

// Round 17
// 342.059 us; speedup vs baseline: 1.2139x; 1.0039x over previous
//
#include <hip/hip_runtime.h>
#include <math.h>

// Problem constants
#define NB 8
#define NT 2048
#define NC 128
#define NLM 64
#define NS 4
#define QROWS 2049
#define NCH 32  // 2048 / 64 chunks

#define TWO_LOG2E 2.885390081777927f
#define LOG2E_F 1.4426950408889634f

__device__ __forceinline__ float rcp_fast(float x) {
  return __builtin_amdgcn_rcpf(x);
}

__device__ __forceinline__ float readlane_f(float v, int lane) {
  return __int_as_float(__builtin_amdgcn_readlane(__float_as_int(v), lane));
}

// Raw v_exp_f32 (2^x). Safe here: |y| bounded ~12, far from denorm/inf
// edges where the libm denorm-guard sequence matters.
__device__ __forceinline__ float exp2_fast(float x) {
  float r;
  asm("v_exp_f32 %0, %1" : "=v"(r) : "v"(x));
  return r;
}

// HW trig in revolutions with REQUIRED v_fract reduction (R27, verified:
// absmax unchanged vs libm).
__device__ __forceinline__ float fract_fast(float x) {
  float r;
  asm("v_fract_f32 %0, %1" : "=v"(r) : "v"(x));
  return r;
}
__device__ __forceinline__ float sin_rev(float r) {
  float d;
  asm("v_sin_f32 %0, %1" : "=v"(d) : "v"(r));
  return d;
}
__device__ __forceinline__ float cos_rev(float r) {
  float d;
  asm("v_cos_f32 %0, %1" : "=v"(d) : "v"(r));
  return d;
}

// ---------------------------------------------------------------------------
// Tiled 64-step local linear scan (forward substitution); all indices
// compile-time so q[4][16] stays in VGPRs. (Used by k23's logZ branch.)
// ---------------------------------------------------------------------------
template <typename PF, typename DF>
__device__ __forceinline__ void tri_scan64(PF P, DF D, float q[4][16]) {
#pragma unroll
  for (int tau = 0; tau < 4; ++tau) {
    float acc[16];
#pragma unroll
    for (int i = 0; i < 16; ++i) acc[i] = D(tau * 16 + i);
#pragma unroll
    for (int p = 0; p < 4; ++p) {
      if (p < tau) {
#pragma unroll
        for (int i = 0; i < 16; ++i) {
          const int t = tau * 16 + i;
#pragma unroll
          for (int i2 = 0; i2 < 16; ++i2) {
            acc[i] = fmaf(P(t, t - (p * 16 + i2) - 1), q[p][i2], acc[i]);
          }
        }
      }
    }
#pragma unroll
    for (int i = 0; i < 16; ++i) {
      const int t = tau * 16 + i;
#pragma unroll
      for (int i2 = 0; i2 < 16; ++i2) {
        if (i2 < i) acc[i] = fmaf(P(t, i - i2 - 1), q[tau][i2], acc[i]);
      }
      q[tau][i] = acc[i];
    }
  }
}

// K1 v3 (R27, measured): R22 structure + fract-reduced HW trig. Passed at
// absmax 4.9e-4; contributed ~-4.6us to total.
__global__ __launch_bounds__(256) void k1_uv(
    const float* __restrict__ x, const float* __restrict__ W,
    const float* __restrict__ bias, const float* __restrict__ phiw,
    float* __restrict__ Q) {
  __shared__ __align__(16) float xs[16][128];  // 8 KB
  __shared__ float us[16][256];                // 16 KB
  const int tid = threadIdx.x;
  const int j = tid & 127;  // column
  const int h = tid >> 7;   // row-half: rows h*8 .. h*8+7
  const int r0 = h * 8;
  const int bt0 = blockIdx.x * 16;
  {
    // 16 rows x 128 cols = 512 float4; 256 threads -> 2 each
    const float4* x4 = (const float4*)(x + (long)bt0 * NC);
    ((float4*)xs)[tid] = x4[tid];
    ((float4*)xs)[tid + 256] = x4[tid + 256];
  }
  __syncthreads();
  float z[8];
  const float bj = bias[j];
#pragma unroll
  for (int r = 0; r < 8; ++r) z[r] = bj;
  for (int k = 0; k < 128; ++k) {
    float w = W[k * 128 + j];
#pragma unroll
    for (int r = 0; r < 8; ++r) z[r] = fmaf(xs[r0 + r][k], w, z[r]);
  }
  const float rs = 0.08838834764831845f;   // 1/sqrt(128)
  const float inv2pi = 0.15915494309189535f;  // 1/(2*pi)
#pragma unroll
  for (int r = 0; r < 8; ++r) {
    float rf = fract_fast(z[r] * inv2pi);  // revolutions, reduced to [0,1)
    us[r0 + r][j] = cos_rev(rf) * rs;
    us[r0 + r][128 + j] = sin_rev(rf) * rs;
  }
  __syncthreads();
  float a[8];
#pragma unroll
  for (int r = 0; r < 8; ++r) a[r] = 0.f;
  for (int k = 0; k < 256; ++k) {
    float w = phiw[k * 128 + j];
#pragma unroll
    for (int r = 0; r < 8; ++r) a[r] = fmaf(us[r0 + r][k], w, a[r]);
  }
#pragma unroll
  for (int r = 0; r < 8; ++r) {
    int bt = bt0 + r0 + r;
    int b = bt >> 11, t = bt & 2047;
    Q[(b * QROWS + t + 1) * NC + j] = a[r];
  }
}

// K23 merged: blocks 0..255 = k2a (per-chunk raw sums of V);
//             blocks 256..259 = k3ab (serial logZ chunk evolution, per s).
__global__ __launch_bounds__(128) void k23_sums_logz(
    const float* __restrict__ Q, float* __restrict__ S2,
    const float* __restrict__ logw, float* __restrict__ logZt) {
  __shared__ float4 part[4][32];
  __shared__ float wx[64];
  __shared__ float mTs[64][65];
  __shared__ float Zr[64];
  const int x = blockIdx.x;
  const int tid = threadIdx.x;
  if (x < 256) {
    const int b = x >> 5, ch = x & 31;
    const int g = tid >> 5, c4 = tid & 31;
    const float4* Q4 = (const float4*)(Q + (long)(b * QROWS + ch * 64 + 1) * NC);
    float4 acc = make_float4(0.f, 0.f, 0.f, 0.f);
#pragma unroll
    for (int i = 0; i < 16; ++i) {
      float4 v = Q4[(g * 16 + i) * 32 + c4];
      acc.x += v.x; acc.y += v.y; acc.z += v.z; acc.w += v.w;
    }
    part[g][c4] = acc;
    __syncthreads();
    if (g == 0) {
      float4 p0 = part[0][c4], p1 = part[1][c4], p2 = part[2][c4], p3 = part[3][c4];
      ((float4*)(S2 + (long)(b * NCH + ch) * NC))[c4] =
          make_float4(p0.x + p1.x + p2.x + p3.x, p0.y + p1.y + p2.y + p3.y,
                      p0.z + p1.z + p2.z + p3.z, p0.w + p1.w + p2.w + p3.w);
    }
  } else {
    const int s = x - 256;
    const int j = tid;
    if (j < 64) wx[j] = __expf(logw[s * NLM + j]);
    __syncthreads();
    if (j < 64) {
      float q[4][16];
      tri_scan64([&](int t, int l) { return wx[l]; },
                 [&](int t) { int l = t + j; return (l < 64) ? wx[l] : 0.f; }, q);
#pragma unroll
      for (int tau = 0; tau < 4; ++tau)
#pragma unroll
        for (int i = 0; i < 16; ++i) mTs[j][tau * 16 + i] = q[tau][i];
    }
    const int t = j;
    if (t < 64) Zr[t] = (t == 0) ? 1.f : 0.f;
    if (t == 0) logZt[s * QROWS] = 0.f;
    float off = 0.f;
    __syncthreads();
    for (int ch = 0; ch < NCH; ++ch) {
      float acc = 0.f, mx = 0.f;
      if (t < 64) {
#pragma unroll 8
        for (int jj = 0; jj < 64; ++jj) acc = fmaf(mTs[jj][t], Zr[jj], acc);
        logZt[s * QROWS + ch * 64 + 1 + t] = logf(acc) + off;
        mx = acc;
#pragma unroll
        for (int o = 32; o; o >>= 1) mx = fmaxf(mx, __shfl_xor(mx, o));
      }
      __syncthreads();
      if (t < 64) {
        Zr[63 - t] = acc / mx;
        off += logf(mx);
      }
      __syncthreads();
    }
  }
}

// KB merged: blocks 0..127 = k5a_basis; blocks 128..383 = k2c (prefix fixup).
// Phase 0 uses the logsumexp identity: pi[t][l] = exp(lw[l] + logZ[t-l]
// - logZ[t+1]). Solve is the statically-tiled q[4][16] left-looking blocked
// substitution (R13).
__global__ __launch_bounds__(128) void kb_basis_fix(
    const float* __restrict__ logw, const float* __restrict__ logZt,
    float* __restrict__ pig, float* __restrict__ rt, float* __restrict__ ctT,
    float* __restrict__ klocal, float* __restrict__ Q,
    const float* __restrict__ S2) {
  // sbuf: [0,4096) psd (pi [t][l]); [4096,8192) Pts (Pt [t][t']);
  //       [8192,16384) Dl ([t][u], u=0..127). After the scan, Rl (stride 65)
  //       aliases [0,8192).
  __shared__ __align__(16) float sbuf[16384];  // 64 KB
  __shared__ float lzs[128];  // LOG2E * logZ[ch*64-63+i], i=0..127
  __shared__ float lws[64];   // LOG2E * logw
  __shared__ float4 gsum[4][32];
  float* psd = sbuf;
  float* Pts = sbuf + 4096;
  float* Dl = sbuf + 8192;
  float* Rl = sbuf;  // stride 65, valid after scan barrier
  const int x = blockIdx.x;
  const int tid = threadIdx.x;
  if (x < 128) {
    const int s = x >> 5, ch = x & 31;
    {
      int idx = ch * 64 - 63 + tid;  // max ch*64+64 <= 2048, in bounds
      lzs[tid] = (idx >= 0) ? logZt[s * QROWS + idx] * LOG2E_F : -INFINITY;
      if (tid < 64) lws[tid] = logw[s * NLM + tid] * LOG2E_F;
    }
    __syncthreads();
    {
      const int l = tid & 63, wv = tid >> 6;
      const float lw2 = lws[l];
      for (int tt = wv; tt < 64; tt += 2) {
        // la2 - lzn2 <= 0 by construction (logZ[t+1] = logsumexp of row)
        float e2 = lw2 + lzs[tt + 63 - l] - lzs[tt + 64];
        float pv = __builtin_exp2f(e2);
        psd[tt * 64 + l] = pv;
        pig[((long)s * NT + ch * 64 + tt) * NLM + l] = pv;
      }
    }
    __syncthreads();
    // Pt[t][t'] = psd[t][t-t'-1] (t'<t) else 0  (32 elems/thread)
    for (int i = tid; i < 4096; i += 128) {
      int t = i >> 6, tp = i & 63;
      Pts[i] = (tp < t) ? psd[t * 64 + (t - tp - 1)] : 0.f;
    }
    // Dl[t][u]: u<64 identity col u; u>=64 history col j=u-64 (64 elems/thread)
    for (int i = tid; i < 8192; i += 128) {
      int t = i >> 7, u = i & 127;
      float d;
      if (u < 64) {
        d = (t == u) ? 1.f : 0.f;
      } else {
        int l = t + (u - 64);
        d = (l < 64) ? psd[t * 64 + l] : 0.f;
      }
      Dl[i] = d;
    }
    __syncthreads();
    // unified forward substitution — statically tiled q[4][16], left-looking
    float q[4][16];
    const float* Dcol = Dl + tid;
#pragma unroll
    for (int tau = 0; tau < 4; ++tau) {
      float acc[16];
#pragma unroll
      for (int i = 0; i < 16; ++i) acc[i] = Dcol[(tau * 16 + i) * 128];
      // full 16x16 blocks from previous tiles (float4 broadcast loads)
#pragma unroll
      for (int p = 0; p < 4; ++p) {
        if (p < tau) {
#pragma unroll
          for (int i = 0; i < 16; ++i) {
            const int tr = tau * 16 + i;
            float a = acc[i];
#pragma unroll
            for (int q4 = 0; q4 < 4; ++q4) {
              float4 p4 = *(const float4*)&Pts[tr * 64 + p * 16 + q4 * 4];
              a = fmaf(p4.x, q[p][4 * q4 + 0], a);
              a = fmaf(p4.y, q[p][4 * q4 + 1], a);
              a = fmaf(p4.z, q[p][4 * q4 + 2], a);
              a = fmaf(p4.w, q[p][4 * q4 + 3], a);
            }
            acc[i] = a;
          }
        }
      }
      // serial intra-tile triangle (scalar broadcast loads)
#pragma unroll
      for (int i = 0; i < 16; ++i) {
        const int tr = tau * 16 + i;
        float a = acc[i];
#pragma unroll
        for (int i2 = 0; i2 < 16; ++i2) {
          if (i2 < i) a = fmaf(Pts[tr * 64 + tau * 16 + i2], q[tau][i2], a);
        }
        q[tau][i] = a;
      }
    }
    __syncthreads();  // psd/Pts dead; Rl may now alias them
    if (tid < 64) {
      const int tp = tid;  // impulse column
      float* rrow = rt + (((long)s * NCH + ch) * 64 + tp) * 64;  // [tp][t]
#pragma unroll
      for (int t4 = 0; t4 < 16; ++t4)
        ((float4*)rrow)[t4] = make_float4(
            q[t4 >> 2][4 * (t4 & 3) + 0], q[t4 >> 2][4 * (t4 & 3) + 1],
            q[t4 >> 2][4 * (t4 & 3) + 2], q[t4 >> 2][4 * (t4 & 3) + 3]);
#pragma unroll
      for (int tt = 0; tt < 4; ++tt)
#pragma unroll
        for (int i = 0; i < 16; ++i) Rl[tp * 65 + tt * 16 + i] = q[tt][i];
    } else {
      const int j = tid - 64;  // history lookback j+1
      float* ctb = ctT + ((long)s * NCH + ch) * 4096;  // [t][j]
#pragma unroll
      for (int tt = 0; tt < 4; ++tt)
#pragma unroll
        for (int i = 0; i < 16; ++i) ctb[(tt * 16 + i) * 64 + j] = q[tt][i];
    }
    __syncthreads();
    if (tid < 64) {  // klocal[t] = sum_tp R[t][tp]
      float acc = 0.f;
#pragma unroll 8
      for (int tp = 0; tp < 64; ++tp) acc += Rl[tp * 65 + tid];
      klocal[((long)s * NCH + ch) * 64 + tid] = acc;
    }
  } else {
    const int y = x - 128;
    const int b = y >> 5, ch = y & 31;
    const int g = tid >> 5, c4 = tid & 31;
    if (ch == 0 && g == 0)
      ((float4*)(Q + (long)(b * QROWS) * NC))[c4] = make_float4(0.f, 0.f, 0.f, 0.f);
    float4 run = make_float4(0.f, 0.f, 0.f, 0.f);
    for (int i = 0; i < ch; ++i) {
      float4 v = ((const float4*)(S2 + (long)(b * NCH + i) * NC))[c4];
      run.x += v.x; run.y += v.y; run.z += v.z; run.w += v.w;
    }
    float4* Q4 = (float4*)(Q + (long)(b * QROWS + ch * 64 + 1) * NC);
    float4 vbuf[16];
#pragma unroll
    for (int i = 0; i < 16; ++i) vbuf[i] = Q4[(g * 16 + i) * 32 + c4];
    {
      float4 gs = make_float4(0.f, 0.f, 0.f, 0.f);
#pragma unroll
      for (int i = 0; i < 16; ++i) {
        gs.x += vbuf[i].x; gs.y += vbuf[i].y; gs.z += vbuf[i].z; gs.w += vbuf[i].w;
      }
      gsum[g][c4] = gs;
    }
    __syncthreads();
    for (int gp = 0; gp < 3; ++gp) {
      if (gp < g) {
        float4 v = gsum[gp][c4];
        run.x += v.x; run.y += v.y; run.z += v.z; run.w += v.w;
      }
    }
#pragma unroll
    for (int i = 0; i < 16; ++i) {
      run.x += vbuf[i].x; run.y += vbuf[i].y; run.z += vbuf[i].z; run.w += vbuf[i].w;
      Q4[(g * 16 + i) * 32 + c4] = run;
    }
  }
}

// K4 v6 (R23, measured): scalar-path weights confirmed — left top-5
// (<61.3us, was 63.5). readfirstlane-proven-uniform pi rows lower to
// s_load; weights arrive as the fma's SGPR operand, zero readlanes.
__global__ __launch_bounds__(256) void k4_e(
    const float* __restrict__ Q, const float* __restrict__ pi,
    const float* __restrict__ phib, float* __restrict__ eq) {
  __shared__ float Qw[68][64];  // 17 KB
  const int b = blockIdx.x;
  const int t0 = blockIdx.y * 4;
  const int half = blockIdx.z;
  const int tid = threadIdx.x;
  for (int i = tid; i < 68 * 64; i += 256) {
    int r = i >> 6, cc = i & 63;
    int tau = t0 - 63 + r;
    Qw[r][cc] = (tau >= 0) ? Q[(b * QROWS + tau) * NC + half * 64 + cc] : 0.f;
  }
  const int c = tid & 63, tg = tid >> 6;  // c == lane id; tg == t-row
  // ti is wave-uniform (tg = tid>>6); readfirstlane makes that provable so
  // the weight loads scalarize to s_load (SGPR operands, no readlanes).
  const int ti = __builtin_amdgcn_readfirstlane(t0 + tg);
  const float* p0 = pi + ((long)0 * NT + ti) * NLM;
  const float* p1 = pi + ((long)1 * NT + ti) * NLM;
  const float* p2 = pi + ((long)2 * NT + ti) * NLM;
  const float* p3 = pi + ((long)3 * NT + ti) * NLM;
  __syncthreads();
  const float pb2 = phib[half * 64 + c] * TWO_LOG2E;
  const float Qt = Qw[tg + 64][c];
  float a0 = 0.f, a1 = 0.f, a2 = 0.f, a3 = 0.f;
#pragma unroll
  for (int lc = 0; lc < 4; ++lc) {
    float v[16];
#pragma unroll
    for (int u = 0; u < 16; ++u) {
      const int l = lc * 16 + u;
      const float cl = TWO_LOG2E / (float)(l + 9);  // folded constant
      float y = (Qt - Qw[tg + 63 - l][c]) * cl + pb2;
      v[u] = rcp_fast(exp2_fast(y) + 1.f);
    }
#pragma unroll
    for (int u = 0; u < 16; ++u) {
      const int l = lc * 16 + u;
      a0 = fmaf(p0[l], v[u], a0);
      a1 = fmaf(p1[l], v[u], a1);
      a2 = fmaf(p2[l], v[u], a2);
      a3 = fmaf(p3[l], v[u], a3);
    }
  }
  const long base = half * 64 + c;
  eq[((long)(0 * 8 + b) * NT + ti) * NC + base] = fmaf(-2.f, a0, 1.f);
  eq[((long)(1 * 8 + b) * NT + ti) * NC + base] = fmaf(-2.f, a1, 1.f);
  eq[((long)(2 * 8 + b) * NT + ti) * NC + base] = fmaf(-2.f, a2, 1.f);
  eq[((long)(3 * 8 + b) * NT + ti) * NC + base] = fmaf(-2.f, a3, 1.f);
}

// K5a-data: qlocal = R @ e per (s,b,chunk) — tiled GEMM, 8t x 8c per lane.
__global__ __launch_bounds__(128) void k5a_data(const float* __restrict__ rt,
                                                float* __restrict__ eq) {
  __shared__ __align__(16) float rts[4096];    // [tp][t] 16 KB
  __shared__ __align__(16) float es[64][128];  // 32 KB
  const int sb = blockIdx.x;  // s*8+b
  const int s = sb >> 3;
  const int ch = blockIdx.y;
  const int tid = threadIdx.x;
  const float4* rsrc = (const float4*)(rt + ((long)s * NCH + ch) * 4096);
#pragma unroll
  for (int i = 0; i < 8; ++i) ((float4*)rts)[tid + 128 * i] = rsrc[tid + 128 * i];
  float* qb = eq + ((long)sb * NT + ch * 64) * NC;
  const float4* esrc = (const float4*)qb;
#pragma unroll
  for (int i = 0; i < 16; ++i) ((float4*)es)[tid + 128 * i] = esrc[tid + 128 * i];
  __syncthreads();
  const int t0 = (tid >> 4) * 8;  // 8 t-tiles
  const int c0 = (tid & 15) * 8;  // 16 c-tiles
  float acc[8][8];
#pragma unroll
  for (int i = 0; i < 8; ++i)
#pragma unroll
    for (int k = 0; k < 8; ++k) acc[i][k] = 0.f;
  for (int tp = 0; tp < 64; ++tp) {
    if (tp <= t0 + 7) {  // R is lower-triangular
      float4 r0 = *(const float4*)&rts[tp * 64 + t0];
      float4 r1 = *(const float4*)&rts[tp * 64 + t0 + 4];
      float4 e0 = *(const float4*)&es[tp][c0];
      float4 e1 = *(const float4*)&es[tp][c0 + 4];
      float rr[8] = {r0.x, r0.y, r0.z, r0.w, r1.x, r1.y, r1.z, r1.w};
      float ee[8] = {e0.x, e0.y, e0.z, e0.w, e1.x, e1.y, e1.z, e1.w};
#pragma unroll
      for (int i = 0; i < 8; ++i)
#pragma unroll
      for (int k = 0; k < 8; ++k) acc[i][k] = fmaf(rr[i], ee[k], acc[i][k]);
    }
  }
#pragma unroll
  for (int i = 0; i < 8; ++i) {
    float4* dst = (float4*)(qb + (t0 + i) * NC + c0);
    dst[0] = make_float4(acc[i][0], acc[i][1], acc[i][2], acc[i][3]);
    dst[1] = make_float4(acc[i][4], acc[i][5], acc[i][6], acc[i][7]);
  }
}

// K5b v2 (R13): cross-chunk combine; cr chunk staged once per block through
// padded LDS (stride 65 => conflict-free), double-buffered across chunks;
// 4 waves per block, 4 channels per wave. History h broadcast via
// v_readlane. Blocks 0..255 = q-scan; blocks 256..259 = k-scan.
__global__ __launch_bounds__(256) void k5b_scan(const float* __restrict__ ctT,
                                                const float* __restrict__ klocal,
                                                float* __restrict__ eq,
                                                float* __restrict__ kout) {
  __shared__ float crs[2][64 * 65];  // 32.5 KB, padded stride 65
  const int tid = threadIdx.x;
  const int t = tid & 63;
  const int w = tid >> 6;
  const int bid = blockIdx.x;
  const bool isq = bid < 256;
  const int s = isq ? ((bid & 7) >> 1) : (bid - 256);
  const float* ctTs = ctT + (long)s * NCH * 4096;

  // staging geometry: thread -> (row sr, 16-float quarter sq); 16 floats each
  const int sr = tid >> 2;
  const int sq = (tid & 3) * 16;
  float4 stg0, stg1, stg2, stg3;

#define K5B_STAGE_LOAD(CH)                                                    \
  {                                                                           \
    const float4* p_ = (const float4*)(ctTs + (CH)*4096 + sr * 64 + sq);      \
    stg0 = p_[0]; stg1 = p_[1]; stg2 = p_[2]; stg3 = p_[3];                   \
  }
#define K5B_STAGE_WRITE(BUF)                                                  \
  {                                                                           \
    float* d_ = &crs[BUF][sr * 65 + sq];                                      \
    d_[0] = stg0.x;  d_[1] = stg0.y;  d_[2] = stg0.z;  d_[3] = stg0.w;        \
    d_[4] = stg1.x;  d_[5] = stg1.y;  d_[6] = stg1.z;  d_[7] = stg1.w;        \
    d_[8] = stg2.x;  d_[9] = stg2.y;  d_[10] = stg2.z; d_[11] = stg2.w;       \
    d_[12] = stg3.x; d_[13] = stg3.y; d_[14] = stg3.z; d_[15] = stg3.w;       \
  }

  // q-branch mapping: per (s,b) 8 blocks x 4 waves x 4 channels = 128 ch
  const int g = bid >> 3;
  const int bb = g & 7, pp = g >> 3;  // pp 0..3 (q-blocks)
  const int hp = bid & 1;
  const int c0 = ((((pp << 1) | hp) << 2) | w) * 4;  // slice*4, slice 0..31
  const int sb = s * 8 + bb;
  float* eqb = eq + (long)sb * NT * NC + c0;

  float hv0 = 0.f, hv1 = 0.f, hv2 = 0.f, hv3 = 0.f;  // q history (per lane t)
  float hk = 0.f;                                    // k history

  K5B_STAGE_LOAD(0)
  K5B_STAGE_WRITE(0)
  __syncthreads();
#pragma unroll 1
  for (int ch = 0; ch < NCH; ++ch) {
    const int cur = ch & 1;
    if (ch + 1 < NCH) K5B_STAGE_LOAD(ch + 1)  // issue early; lands at write
    if (isq) {
      const float* cr = &crs[cur][t * 65];
      float4 ql = *(const float4*)(eqb + (long)(ch * 64 + t) * NC);
      float a0 = 0.f, a1 = 0.f, a2 = 0.f, a3 = 0.f;
#pragma unroll
      for (int j = 0; j < 64; ++j) {
        float cv = cr[j];
        a0 = fmaf(cv, readlane_f(hv0, 63 - j), a0);
        a1 = fmaf(cv, readlane_f(hv1, 63 - j), a1);
        a2 = fmaf(cv, readlane_f(hv2, 63 - j), a2);
        a3 = fmaf(cv, readlane_f(hv3, 63 - j), a3);
      }
      hv0 = a0 + ql.x; hv1 = a1 + ql.y; hv2 = a2 + ql.z; hv3 = a3 + ql.w;
      *(float4*)(eqb + (long)(ch * 64 + t) * NC) =
          make_float4(hv0, hv1, hv2, hv3);
    } else if (tid < 64) {
      const float* cr = &crs[cur][t * 65];
      float acc = klocal[((long)s * NCH + ch) * 64 + t];
#pragma unroll
      for (int j = 0; j < 64; ++j)
        acc = fmaf(cr[j], readlane_f(hk, 63 - j), acc);
      kout[s * NT + ch * 64 + t] = acc;
      hk = acc;
    }
    __syncthreads();  // all waves done READING crs[cur^1] (chunk ch-1)
    if (ch + 1 < NCH) K5B_STAGE_WRITE(cur ^ 1)
    __syncthreads();  // crs[cur^1] ready for chunk ch+1
  }
#undef K5B_STAGE_LOAD
#undef K5B_STAGE_WRITE
}

// K6 v6 (R29): fused split-K. R28 measured: split-K gave k6 ~60us (from
// 63.5) but k7_add's extra pass (+24MB HBM round-trip) ate the gain
// (total flat). Occupancy counter stayed ~33% in EVERY k6 config
// (R23/R26/R28) — not the limiter. This version keeps split-K's win and
// deletes its overhead: 512-thread blocks, waves 0-3 = K-half 0, waves
// 4-7 = K-half 1 over ONE 32KB rsdata staging; z=1 partials via 8KB LDS
// (psum, lane-indexed => conflict-free); z=0 adds + writes. No k7 pass.
// Inner loop is byte-identical to the R23 local optimum (8 rows x 1 col,
// 8 fma/load, 8 chains). LDS 40KB -> 4 blocks/CU x 8 waves = 32 waves/CU.
__global__ __launch_bounds__(512) void k6_mix(
    const float* __restrict__ q, const float* __restrict__ kout,
    const float* __restrict__ anchor, const float* __restrict__ mixw,
    const float* __restrict__ mixb, float* __restrict__ out) {
  __shared__ __align__(16) float rsdata[16][512];  // 32 KB
  __shared__ float psum[16][128];                  // 8 KB
  const int b = blockIdx.x;
  const int t0 = blockIdx.y * 16;
  const int tid = threadIdx.x;
  for (int i = tid; i < 16 * 512; i += 512) {
    int r = i >> 9, sc = i & 511;
    int s = sc >> 7, c = sc & 127;
    int ti = t0 + r;
    float qv = q[((long)(s * 8 + b) * NT + ti) * NC + c];
    float kv = kout[s * NT + ti];
    float d1 = rcp_fast(kv + 16.f);
    rsdata[r][sc] = (qv + 16.f * anchor[sc]) * d1 * (kv * d1);
  }
  __syncthreads();
  const int co = tid & 127;
  const int hf = (tid >> 7) & 1;  // row-half
  const int zh = tid >> 8;        // K-half
  const int r0 = hf * 8;
  const int k0 = zh * 256;
  const float init = (zh == 0) ? mixb[co] : 0.f;
  float acc[8];
#pragma unroll
  for (int r = 0; r < 8; ++r) acc[r] = init;
  const float* mw = mixw + (long)k0 * 128 + co;
  for (int kk = 0; kk < 256; kk += 4) {
    float wa = mw[(kk + 0) * 128];
    float wb = mw[(kk + 1) * 128];
    float wc = mw[(kk + 2) * 128];
    float wd = mw[(kk + 3) * 128];
#pragma unroll
    for (int r = 0; r < 8; ++r) {
      float4 rv = *(const float4*)&rsdata[r0 + r][k0 + kk];
      acc[r] = fmaf(rv.x, wa, acc[r]);
      acc[r] = fmaf(rv.y, wb, acc[r]);
      acc[r] = fmaf(rv.z, wc, acc[r]);
      acc[r] = fmaf(rv.w, wd, acc[r]);
    }
  }
  if (zh == 1) {
#pragma unroll
    for (int r = 0; r < 8; ++r) psum[r0 + r][co] = acc[r];
  }
  __syncthreads();
  if (zh == 0) {
#pragma unroll
    for (int r = 0; r < 8; ++r)
      out[((long)b * NT + t0 + r0 + r) * NC + co] = acc[r] + psum[r0 + r][co];
  }
}

extern "C" void kernel_launch(void* const* d_in, const int* in_sizes, int n_in,
                              void* d_out, int out_size, void* d_ws, size_t ws_size,
                              hipStream_t stream) {
  const float* x = (const float*)d_in[0];
  const float* W = (const float*)d_in[1];
  const float* bias = (const float*)d_in[2];
  const float* phiw = (const float*)d_in[3];
  const float* phib = (const float*)d_in[4];
  const float* anchor = (const float*)d_in[5];
  const float* logw = (const float*)d_in[6];
  const float* mixw = (const float*)d_in[7];
  const float* mixb = (const float*)d_in[8];
  float* out = (float*)d_out;

  float* ws = (float*)d_ws;
  float* Q = ws;                                     // 8*2049*128 = 2,098,176
  float* pi = Q + (long)NB * QROWS * NC;             // 4*2048*64  =   524,288
  float* eq = pi + (long)NS * NT * NLM;              // 32*2048*128= 8,388,608
  float* coefTT = eq + (long)NS * NB * NT * NC;      //               524,288
  float* rtb = coefTT + (long)NS * NCH * 4096;       //               524,288
  float* klocal = rtb + (long)NS * NCH * 4096;       //                 8,192
  float* kout = klocal + (long)NS * NCH * 64;        //                 8,192
  float* logZt = kout + (long)NS * NT;               //                 8,196
  float* S2 = logZt + (long)NS * QROWS;              //                32,768

  hipLaunchKernelGGL(k1_uv, dim3(NB * NT / 16), dim3(256), 0, stream, x, W, bias, phiw, Q);
  hipLaunchKernelGGL(k23_sums_logz, dim3(260), dim3(128), 0, stream, Q, S2, logw, logZt);
  hipLaunchKernelGGL(kb_basis_fix, dim3(384), dim3(128), 0, stream, logw, logZt, pi, rtb, coefTT, klocal, Q, S2);
  hipLaunchKernelGGL(k4_e, dim3(NB, NT / 4, 2), dim3(256), 0, stream, Q, pi, phib, eq);
  hipLaunchKernelGGL(k5a_data, dim3(NS * NB, NCH), dim3(128), 0, stream, rtb, eq);
  hipLaunchKernelGGL(k5b_scan, dim3(260), dim3(256), 0, stream, coefTT, klocal, eq, kout);
  hipLaunchKernelGGL(k6_mix, dim3(NB, NT / 16), dim3(512), 0, stream, eq, kout, anchor, mixw, mixb, out);
}

// Round 18
// 331.760 us; speedup vs baseline: 1.2516x; 1.0310x over previous
//
#include <hip/hip_runtime.h>
#include <math.h>

// Problem constants
#define NB 8
#define NT 2048
#define NC 128
#define NLM 64
#define NS 4
#define QROWS 2049
#define NCH 32  // 2048 / 64 chunks

#define TWO_LOG2E 2.885390081777927f
#define LOG2E_F 1.4426950408889634f

typedef __attribute__((__ext_vector_type__(8))) short short8v;   // 8 bf16
typedef __attribute__((__ext_vector_type__(4))) float f32x4v;    // MFMA acc

__device__ __forceinline__ float rcp_fast(float x) {
  return __builtin_amdgcn_rcpf(x);
}

__device__ __forceinline__ float readlane_f(float v, int lane) {
  return __int_as_float(__builtin_amdgcn_readlane(__float_as_int(v), lane));
}

// Raw v_exp_f32 (2^x). Safe here: |y| bounded ~12.
__device__ __forceinline__ float exp2_fast(float x) {
  float r;
  asm("v_exp_f32 %0, %1" : "=v"(r) : "v"(x));
  return r;
}

// HW trig in revolutions with REQUIRED v_fract reduction (R27, verified).
__device__ __forceinline__ float fract_fast(float x) {
  float r;
  asm("v_fract_f32 %0, %1" : "=v"(r) : "v"(x));
  return r;
}
__device__ __forceinline__ float sin_rev(float r) {
  float d;
  asm("v_sin_f32 %0, %1" : "=v"(d) : "v"(r));
  return d;
}
__device__ __forceinline__ float cos_rev(float r) {
  float d;
  asm("v_cos_f32 %0, %1" : "=v"(d) : "v"(r));
  return d;
}

// bf16 hi/lo split by truncation: v = hi + lo with |err| ~ 2^-16 |v|.
__device__ __forceinline__ void bf16_split(float v, unsigned short* h,
                                           unsigned short* l) {
  unsigned vb = __float_as_uint(v);
  unsigned short hi = (unsigned short)(vb >> 16);
  float hf = __uint_as_float((unsigned)hi << 16);
  float lo = v - hf;  // exact
  *h = hi;
  *l = (unsigned short)(__float_as_uint(lo) >> 16);
}

// ---------------------------------------------------------------------------
// Tiled 64-step local linear scan (forward substitution); all indices
// compile-time so q[4][16] stays in VGPRs. (Used by k23's logZ branch.)
// ---------------------------------------------------------------------------
template <typename PF, typename DF>
__device__ __forceinline__ void tri_scan64(PF P, DF D, float q[4][16]) {
#pragma unroll
  for (int tau = 0; tau < 4; ++tau) {
    float acc[16];
#pragma unroll
    for (int i = 0; i < 16; ++i) acc[i] = D(tau * 16 + i);
#pragma unroll
    for (int p = 0; p < 4; ++p) {
      if (p < tau) {
#pragma unroll
        for (int i = 0; i < 16; ++i) {
          const int t = tau * 16 + i;
#pragma unroll
          for (int i2 = 0; i2 < 16; ++i2) {
            acc[i] = fmaf(P(t, t - (p * 16 + i2) - 1), q[p][i2], acc[i]);
          }
        }
      }
    }
#pragma unroll
    for (int i = 0; i < 16; ++i) {
      const int t = tau * 16 + i;
#pragma unroll
      for (int i2 = 0; i2 < 16; ++i2) {
        if (i2 < i) acc[i] = fmaf(P(t, i - i2 - 1), q[tau][i2], acc[i]);
      }
      q[tau][i] = acc[i];
    }
  }
}

// K1 v3 (R27, measured): R22 structure + fract-reduced HW trig.
__global__ __launch_bounds__(256) void k1_uv(
    const float* __restrict__ x, const float* __restrict__ W,
    const float* __restrict__ bias, const float* __restrict__ phiw,
    float* __restrict__ Q) {
  __shared__ __align__(16) float xs[16][128];  // 8 KB
  __shared__ float us[16][256];                // 16 KB
  const int tid = threadIdx.x;
  const int j = tid & 127;  // column
  const int h = tid >> 7;   // row-half: rows h*8 .. h*8+7
  const int r0 = h * 8;
  const int bt0 = blockIdx.x * 16;
  {
    const float4* x4 = (const float4*)(x + (long)bt0 * NC);
    ((float4*)xs)[tid] = x4[tid];
    ((float4*)xs)[tid + 256] = x4[tid + 256];
  }
  __syncthreads();
  float z[8];
  const float bj = bias[j];
#pragma unroll
  for (int r = 0; r < 8; ++r) z[r] = bj;
  for (int k = 0; k < 128; ++k) {
    float w = W[k * 128 + j];
#pragma unroll
    for (int r = 0; r < 8; ++r) z[r] = fmaf(xs[r0 + r][k], w, z[r]);
  }
  const float rs = 0.08838834764831845f;   // 1/sqrt(128)
  const float inv2pi = 0.15915494309189535f;  // 1/(2*pi)
#pragma unroll
  for (int r = 0; r < 8; ++r) {
    float rf = fract_fast(z[r] * inv2pi);  // revolutions, reduced to [0,1)
    us[r0 + r][j] = cos_rev(rf) * rs;
    us[r0 + r][128 + j] = sin_rev(rf) * rs;
  }
  __syncthreads();
  float a[8];
#pragma unroll
  for (int r = 0; r < 8; ++r) a[r] = 0.f;
  for (int k = 0; k < 256; ++k) {
    float w = phiw[k * 128 + j];
#pragma unroll
    for (int r = 0; r < 8; ++r) a[r] = fmaf(us[r0 + r][k], w, a[r]);
  }
#pragma unroll
  for (int r = 0; r < 8; ++r) {
    int bt = bt0 + r0 + r;
    int b = bt >> 11, t = bt & 2047;
    Q[(b * QROWS + t + 1) * NC + j] = a[r];
  }
}

// K23 merged: blocks 0..255 = k2a (per-chunk raw sums of V);
//             blocks 256..259 = k3ab (serial logZ chunk evolution, per s).
__global__ __launch_bounds__(128) void k23_sums_logz(
    const float* __restrict__ Q, float* __restrict__ S2,
    const float* __restrict__ logw, float* __restrict__ logZt) {
  __shared__ float4 part[4][32];
  __shared__ float wx[64];
  __shared__ float mTs[64][65];
  __shared__ float Zr[64];
  const int x = blockIdx.x;
  const int tid = threadIdx.x;
  if (x < 256) {
    const int b = x >> 5, ch = x & 31;
    const int g = tid >> 5, c4 = tid & 31;
    const float4* Q4 = (const float4*)(Q + (long)(b * QROWS + ch * 64 + 1) * NC);
    float4 acc = make_float4(0.f, 0.f, 0.f, 0.f);
#pragma unroll
    for (int i = 0; i < 16; ++i) {
      float4 v = Q4[(g * 16 + i) * 32 + c4];
      acc.x += v.x; acc.y += v.y; acc.z += v.z; acc.w += v.w;
    }
    part[g][c4] = acc;
    __syncthreads();
    if (g == 0) {
      float4 p0 = part[0][c4], p1 = part[1][c4], p2 = part[2][c4], p3 = part[3][c4];
      ((float4*)(S2 + (long)(b * NCH + ch) * NC))[c4] =
          make_float4(p0.x + p1.x + p2.x + p3.x, p0.y + p1.y + p2.y + p3.y,
                      p0.z + p1.z + p2.z + p3.z, p0.w + p1.w + p2.w + p3.w);
    }
  } else {
    const int s = x - 256;
    const int j = tid;
    if (j < 64) wx[j] = __expf(logw[s * NLM + j]);
    __syncthreads();
    if (j < 64) {
      float q[4][16];
      tri_scan64([&](int t, int l) { return wx[l]; },
                 [&](int t) { int l = t + j; return (l < 64) ? wx[l] : 0.f; }, q);
#pragma unroll
      for (int tau = 0; tau < 4; ++tau)
#pragma unroll
        for (int i = 0; i < 16; ++i) mTs[j][tau * 16 + i] = q[tau][i];
    }
    const int t = j;
    if (t < 64) Zr[t] = (t == 0) ? 1.f : 0.f;
    if (t == 0) logZt[s * QROWS] = 0.f;
    float off = 0.f;
    __syncthreads();
    for (int ch = 0; ch < NCH; ++ch) {
      float acc = 0.f, mx = 0.f;
      if (t < 64) {
#pragma unroll 8
        for (int jj = 0; jj < 64; ++jj) acc = fmaf(mTs[jj][t], Zr[jj], acc);
        logZt[s * QROWS + ch * 64 + 1 + t] = logf(acc) + off;
        mx = acc;
#pragma unroll
        for (int o = 32; o; o >>= 1) mx = fmaxf(mx, __shfl_xor(mx, o));
      }
      __syncthreads();
      if (t < 64) {
        Zr[63 - t] = acc / mx;
        off += logf(mx);
      }
      __syncthreads();
    }
  }
}

// KB merged: blocks 0..127 = k5a_basis; blocks 128..383 = k2c (prefix fixup).
__global__ __launch_bounds__(128) void kb_basis_fix(
    const float* __restrict__ logw, const float* __restrict__ logZt,
    float* __restrict__ pig, float* __restrict__ rt, float* __restrict__ ctT,
    float* __restrict__ klocal, float* __restrict__ Q,
    const float* __restrict__ S2) {
  __shared__ __align__(16) float sbuf[16384];  // 64 KB
  __shared__ float lzs[128];
  __shared__ float lws[64];
  __shared__ float4 gsum[4][32];
  float* psd = sbuf;
  float* Pts = sbuf + 4096;
  float* Dl = sbuf + 8192;
  float* Rl = sbuf;  // stride 65, valid after scan barrier
  const int x = blockIdx.x;
  const int tid = threadIdx.x;
  if (x < 128) {
    const int s = x >> 5, ch = x & 31;
    {
      int idx = ch * 64 - 63 + tid;
      lzs[tid] = (idx >= 0) ? logZt[s * QROWS + idx] * LOG2E_F : -INFINITY;
      if (tid < 64) lws[tid] = logw[s * NLM + tid] * LOG2E_F;
    }
    __syncthreads();
    {
      const int l = tid & 63, wv = tid >> 6;
      const float lw2 = lws[l];
      for (int tt = wv; tt < 64; tt += 2) {
        float e2 = lw2 + lzs[tt + 63 - l] - lzs[tt + 64];
        float pv = __builtin_exp2f(e2);
        psd[tt * 64 + l] = pv;
        pig[((long)s * NT + ch * 64 + tt) * NLM + l] = pv;
      }
    }
    __syncthreads();
    for (int i = tid; i < 4096; i += 128) {
      int t = i >> 6, tp = i & 63;
      Pts[i] = (tp < t) ? psd[t * 64 + (t - tp - 1)] : 0.f;
    }
    for (int i = tid; i < 8192; i += 128) {
      int t = i >> 7, u = i & 127;
      float d;
      if (u < 64) {
        d = (t == u) ? 1.f : 0.f;
      } else {
        int l = t + (u - 64);
        d = (l < 64) ? psd[t * 64 + l] : 0.f;
      }
      Dl[i] = d;
    }
    __syncthreads();
    float q[4][16];
    const float* Dcol = Dl + tid;
#pragma unroll
    for (int tau = 0; tau < 4; ++tau) {
      float acc[16];
#pragma unroll
      for (int i = 0; i < 16; ++i) acc[i] = Dcol[(tau * 16 + i) * 128];
#pragma unroll
      for (int p = 0; p < 4; ++p) {
        if (p < tau) {
#pragma unroll
          for (int i = 0; i < 16; ++i) {
            const int tr = tau * 16 + i;
            float a = acc[i];
#pragma unroll
            for (int q4 = 0; q4 < 4; ++q4) {
              float4 p4 = *(const float4*)&Pts[tr * 64 + p * 16 + q4 * 4];
              a = fmaf(p4.x, q[p][4 * q4 + 0], a);
              a = fmaf(p4.y, q[p][4 * q4 + 1], a);
              a = fmaf(p4.z, q[p][4 * q4 + 2], a);
              a = fmaf(p4.w, q[p][4 * q4 + 3], a);
            }
            acc[i] = a;
          }
        }
      }
#pragma unroll
      for (int i = 0; i < 16; ++i) {
        const int tr = tau * 16 + i;
        float a = acc[i];
#pragma unroll
        for (int i2 = 0; i2 < 16; ++i2) {
          if (i2 < i) a = fmaf(Pts[tr * 64 + tau * 16 + i2], q[tau][i2], a);
        }
        q[tau][i] = a;
      }
    }
    __syncthreads();
    if (tid < 64) {
      const int tp = tid;
      float* rrow = rt + (((long)s * NCH + ch) * 64 + tp) * 64;
#pragma unroll
      for (int t4 = 0; t4 < 16; ++t4)
        ((float4*)rrow)[t4] = make_float4(
            q[t4 >> 2][4 * (t4 & 3) + 0], q[t4 >> 2][4 * (t4 & 3) + 1],
            q[t4 >> 2][4 * (t4 & 3) + 2], q[t4 >> 2][4 * (t4 & 3) + 3]);
#pragma unroll
      for (int tt = 0; tt < 4; ++tt)
#pragma unroll
        for (int i = 0; i < 16; ++i) Rl[tp * 65 + tt * 16 + i] = q[tt][i];
    } else {
      const int j = tid - 64;
      float* ctb = ctT + ((long)s * NCH + ch) * 4096;
#pragma unroll
      for (int tt = 0; tt < 4; ++tt)
#pragma unroll
        for (int i = 0; i < 16; ++i) ctb[(tt * 16 + i) * 64 + j] = q[tt][i];
    }
    __syncthreads();
    if (tid < 64) {
      float acc = 0.f;
#pragma unroll 8
      for (int tp = 0; tp < 64; ++tp) acc += Rl[tp * 65 + tid];
      klocal[((long)s * NCH + ch) * 64 + tid] = acc;
    }
  } else {
    const int y = x - 128;
    const int b = y >> 5, ch = y & 31;
    const int g = tid >> 5, c4 = tid & 31;
    if (ch == 0 && g == 0)
      ((float4*)(Q + (long)(b * QROWS) * NC))[c4] = make_float4(0.f, 0.f, 0.f, 0.f);
    float4 run = make_float4(0.f, 0.f, 0.f, 0.f);
    for (int i = 0; i < ch; ++i) {
      float4 v = ((const float4*)(S2 + (long)(b * NCH + i) * NC))[c4];
      run.x += v.x; run.y += v.y; run.z += v.z; run.w += v.w;
    }
    float4* Q4 = (float4*)(Q + (long)(b * QROWS + ch * 64 + 1) * NC);
    float4 vbuf[16];
#pragma unroll
    for (int i = 0; i < 16; ++i) vbuf[i] = Q4[(g * 16 + i) * 32 + c4];
    {
      float4 gs = make_float4(0.f, 0.f, 0.f, 0.f);
#pragma unroll
      for (int i = 0; i < 16; ++i) {
        gs.x += vbuf[i].x; gs.y += vbuf[i].y; gs.z += vbuf[i].z; gs.w += vbuf[i].w;
      }
      gsum[g][c4] = gs;
    }
    __syncthreads();
    for (int gp = 0; gp < 3; ++gp) {
      if (gp < g) {
        float4 v = gsum[gp][c4];
        run.x += v.x; run.y += v.y; run.z += v.z; run.w += v.w;
      }
    }
#pragma unroll
    for (int i = 0; i < 16; ++i) {
      run.x += vbuf[i].x; run.y += vbuf[i].y; run.z += vbuf[i].z; run.w += vbuf[i].w;
      Q4[(g * 16 + i) * 32 + c4] = run;
    }
  }
}

// K4 v6 (R23, measured): scalar-path weights via readfirstlane s_load.
__global__ __launch_bounds__(256) void k4_e(
    const float* __restrict__ Q, const float* __restrict__ pi,
    const float* __restrict__ phib, float* __restrict__ eq) {
  __shared__ float Qw[68][64];  // 17 KB
  const int b = blockIdx.x;
  const int t0 = blockIdx.y * 4;
  const int half = blockIdx.z;
  const int tid = threadIdx.x;
  for (int i = tid; i < 68 * 64; i += 256) {
    int r = i >> 6, cc = i & 63;
    int tau = t0 - 63 + r;
    Qw[r][cc] = (tau >= 0) ? Q[(b * QROWS + tau) * NC + half * 64 + cc] : 0.f;
  }
  const int c = tid & 63, tg = tid >> 6;
  const int ti = __builtin_amdgcn_readfirstlane(t0 + tg);
  const float* p0 = pi + ((long)0 * NT + ti) * NLM;
  const float* p1 = pi + ((long)1 * NT + ti) * NLM;
  const float* p2 = pi + ((long)2 * NT + ti) * NLM;
  const float* p3 = pi + ((long)3 * NT + ti) * NLM;
  __syncthreads();
  const float pb2 = phib[half * 64 + c] * TWO_LOG2E;
  const float Qt = Qw[tg + 64][c];
  float a0 = 0.f, a1 = 0.f, a2 = 0.f, a3 = 0.f;
#pragma unroll
  for (int lc = 0; lc < 4; ++lc) {
    float v[16];
#pragma unroll
    for (int u = 0; u < 16; ++u) {
      const int l = lc * 16 + u;
      const float cl = TWO_LOG2E / (float)(l + 9);
      float y = (Qt - Qw[tg + 63 - l][c]) * cl + pb2;
      v[u] = rcp_fast(exp2_fast(y) + 1.f);
    }
#pragma unroll
    for (int u = 0; u < 16; ++u) {
      const int l = lc * 16 + u;
      a0 = fmaf(p0[l], v[u], a0);
      a1 = fmaf(p1[l], v[u], a1);
      a2 = fmaf(p2[l], v[u], a2);
      a3 = fmaf(p3[l], v[u], a3);
    }
  }
  const long base = half * 64 + c;
  eq[((long)(0 * 8 + b) * NT + ti) * NC + base] = fmaf(-2.f, a0, 1.f);
  eq[((long)(1 * 8 + b) * NT + ti) * NC + base] = fmaf(-2.f, a1, 1.f);
  eq[((long)(2 * 8 + b) * NT + ti) * NC + base] = fmaf(-2.f, a2, 1.f);
  eq[((long)(3 * 8 + b) * NT + ti) * NC + base] = fmaf(-2.f, a3, 1.f);
}

// K0-prep (R30): transpose mixw -> [c][k] and split into bf16 hi/lo pairs
// for k6's MFMA path. Writes into the DEAD pi workspace (pi unread after
// k4; 524288 floats >= 2*32768). 65536 elems, coalesced reads.
__global__ __launch_bounds__(256) void k0_prep(
    const float* __restrict__ mixw, unsigned short* __restrict__ th,
    unsigned short* __restrict__ tl) {
  const int i = blockIdx.x * 256 + threadIdx.x;  // 0..65535
  const int k = i >> 7, c = i & 127;
  float v = mixw[i];  // mixw[k*128+c]
  unsigned short h, l;
  bf16_split(v, &h, &l);
  th[c * 512 + k] = h;
  tl[c * 512 + k] = l;
}

// K5a-data: qlocal = R @ e per (s,b,chunk) — tiled GEMM, 8t x 8c per lane.
__global__ __launch_bounds__(128) void k5a_data(const float* __restrict__ rt,
                                                float* __restrict__ eq) {
  __shared__ __align__(16) float rts[4096];    // [tp][t] 16 KB
  __shared__ __align__(16) float es[64][128];  // 32 KB
  const int sb = blockIdx.x;
  const int s = sb >> 3;
  const int ch = blockIdx.y;
  const int tid = threadIdx.x;
  const float4* rsrc = (const float4*)(rt + ((long)s * NCH + ch) * 4096);
#pragma unroll
  for (int i = 0; i < 8; ++i) ((float4*)rts)[tid + 128 * i] = rsrc[tid + 128 * i];
  float* qb = eq + ((long)sb * NT + ch * 64) * NC;
  const float4* esrc = (const float4*)qb;
#pragma unroll
  for (int i = 0; i < 16; ++i) ((float4*)es)[tid + 128 * i] = esrc[tid + 128 * i];
  __syncthreads();
  const int t0 = (tid >> 4) * 8;
  const int c0 = (tid & 15) * 8;
  float acc[8][8];
#pragma unroll
  for (int i = 0; i < 8; ++i)
#pragma unroll
    for (int k = 0; k < 8; ++k) acc[i][k] = 0.f;
  for (int tp = 0; tp < 64; ++tp) {
    if (tp <= t0 + 7) {
      float4 r0 = *(const float4*)&rts[tp * 64 + t0];
      float4 r1 = *(const float4*)&rts[tp * 64 + t0 + 4];
      float4 e0 = *(const float4*)&es[tp][c0];
      float4 e1 = *(const float4*)&es[tp][c0 + 4];
      float rr[8] = {r0.x, r0.y, r0.z, r0.w, r1.x, r1.y, r1.z, r1.w};
      float ee[8] = {e0.x, e0.y, e0.z, e0.w, e1.x, e1.y, e1.z, e1.w};
#pragma unroll
      for (int i = 0; i < 8; ++i)
#pragma unroll
        for (int k = 0; k < 8; ++k) acc[i][k] = fmaf(rr[i], ee[k], acc[i][k]);
    }
  }
#pragma unroll
  for (int i = 0; i < 8; ++i) {
    float4* dst = (float4*)(qb + (t0 + i) * NC + c0);
    dst[0] = make_float4(acc[i][0], acc[i][1], acc[i][2], acc[i][3]);
    dst[1] = make_float4(acc[i][4], acc[i][5], acc[i][6], acc[i][7]);
  }
}

// K5b v2 (R13): cross-chunk combine via padded-LDS double buffer.
__global__ __launch_bounds__(256) void k5b_scan(const float* __restrict__ ctT,
                                                const float* __restrict__ klocal,
                                                float* __restrict__ eq,
                                                float* __restrict__ kout) {
  __shared__ float crs[2][64 * 65];  // 32.5 KB
  const int tid = threadIdx.x;
  const int t = tid & 63;
  const int w = tid >> 6;
  const int bid = blockIdx.x;
  const bool isq = bid < 256;
  const int s = isq ? ((bid & 7) >> 1) : (bid - 256);
  const float* ctTs = ctT + (long)s * NCH * 4096;

  const int sr = tid >> 2;
  const int sq = (tid & 3) * 16;
  float4 stg0, stg1, stg2, stg3;

#define K5B_STAGE_LOAD(CH)                                                    \
  {                                                                           \
    const float4* p_ = (const float4*)(ctTs + (CH)*4096 + sr * 64 + sq);      \
    stg0 = p_[0]; stg1 = p_[1]; stg2 = p_[2]; stg3 = p_[3];                   \
  }
#define K5B_STAGE_WRITE(BUF)                                                  \
  {                                                                           \
    float* d_ = &crs[BUF][sr * 65 + sq];                                      \
    d_[0] = stg0.x;  d_[1] = stg0.y;  d_[2] = stg0.z;  d_[3] = stg0.w;        \
    d_[4] = stg1.x;  d_[5] = stg1.y;  d_[6] = stg1.z;  d_[7] = stg1.w;        \
    d_[8] = stg2.x;  d_[9] = stg2.y;  d_[10] = stg2.z; d_[11] = stg2.w;       \
    d_[12] = stg3.x; d_[13] = stg3.y; d_[14] = stg3.z; d_[15] = stg3.w;       \
  }

  const int g = bid >> 3;
  const int bb = g & 7, pp = g >> 3;
  const int hp = bid & 1;
  const int c0 = ((((pp << 1) | hp) << 2) | w) * 4;
  const int sb = s * 8 + bb;
  float* eqb = eq + (long)sb * NT * NC + c0;

  float hv0 = 0.f, hv1 = 0.f, hv2 = 0.f, hv3 = 0.f;
  float hk = 0.f;

  K5B_STAGE_LOAD(0)
  K5B_STAGE_WRITE(0)
  __syncthreads();
#pragma unroll 1
  for (int ch = 0; ch < NCH; ++ch) {
    const int cur = ch & 1;
    if (ch + 1 < NCH) K5B_STAGE_LOAD(ch + 1)
    if (isq) {
      const float* cr = &crs[cur][t * 65];
      float4 ql = *(const float4*)(eqb + (long)(ch * 64 + t) * NC);
      float a0 = 0.f, a1 = 0.f, a2 = 0.f, a3 = 0.f;
#pragma unroll
      for (int j = 0; j < 64; ++j) {
        float cv = cr[j];
        a0 = fmaf(cv, readlane_f(hv0, 63 - j), a0);
        a1 = fmaf(cv, readlane_f(hv1, 63 - j), a1);
        a2 = fmaf(cv, readlane_f(hv2, 63 - j), a2);
        a3 = fmaf(cv, readlane_f(hv3, 63 - j), a3);
      }
      hv0 = a0 + ql.x; hv1 = a1 + ql.y; hv2 = a2 + ql.z; hv3 = a3 + ql.w;
      *(float4*)(eqb + (long)(ch * 64 + t) * NC) =
          make_float4(hv0, hv1, hv2, hv3);
    } else if (tid < 64) {
      const float* cr = &crs[cur][t * 65];
      float acc = klocal[((long)s * NCH + ch) * 64 + t];
#pragma unroll
      for (int j = 0; j < 64; ++j)
        acc = fmaf(cr[j], readlane_f(hk, 63 - j), acc);
      kout[s * NT + ch * 64 + t] = acc;
      hk = acc;
    }
    __syncthreads();
    if (ch + 1 < NCH) K5B_STAGE_WRITE(cur ^ 1)
    __syncthreads();
  }
#undef K5B_STAGE_LOAD
#undef K5B_STAGE_WRITE
}

// K6 v7 (R30): bf16x3 MFMA GEMM. Five scalar-path variants pinned at
// 60-64us with MfmaUtil=0 — the matrix pipe is the one unplayed lever.
// D = Ah·Bh + Ah·Bl + Al·Bh (truncated hi/lo split, rel err ~2^-16,
// dropped Al·Bl ~2^-18 — far inside the ~1e-3 absmax headroom).
// Block = 16 rows x 128 cols; 8 waves each own a 16-col tile; K=512 in
// 16 steps of mfma_f32_16x16x32_bf16. A (rs hi/lo) in LDS stride 520
// (row bank-shift 4 => <=2-way = free). B streamed from pre-transposed
// bf16 mixwT (k0_prep, L2-resident): contiguous 16B/lane — the verified
// gemm_bt fragment pattern. C/D layout col=lane&15, row=(lane>>4)*4+reg
// (HW-verified per guide m89/m91).
__global__ __launch_bounds__(512) void k6_mix(
    const float* __restrict__ q, const float* __restrict__ kout,
    const float* __restrict__ anchor,
    const unsigned short* __restrict__ mixwTh,
    const unsigned short* __restrict__ mixwTl,
    const float* __restrict__ mixb, float* __restrict__ out) {
  __shared__ unsigned short rsh[16][520];  // 16.25 KB
  __shared__ unsigned short rsl[16][520];  // 16.25 KB
  const int b = blockIdx.x;
  const int t0 = blockIdx.y * 16;
  const int tid = threadIdx.x;
  for (int i = tid; i < 16 * 512; i += 512) {
    int r = i >> 9, sc = i & 511;
    int s = sc >> 7, c = sc & 127;
    int ti = t0 + r;
    float qv = q[((long)(s * 8 + b) * NT + ti) * NC + c];
    float kv = kout[s * NT + ti];
    float d1 = rcp_fast(kv + 16.f);
    float v = (qv + 16.f * anchor[sc]) * d1 * (kv * d1);
    unsigned short h, l;
    bf16_split(v, &h, &l);
    rsh[r][sc] = h;
    rsl[r][sc] = l;
  }
  __syncthreads();
  const int w = tid >> 6;       // wave 0..7 owns cols w*16..w*16+15
  const int lane = tid & 63;
  const int mrow = lane & 15;   // A row / B col / C col
  const int kgrp = lane >> 4;   // 0..3
  const int c0w = w * 16;
  const float bias = mixb[c0w + mrow];
  f32x4v acc = {bias, bias, bias, bias};
  const unsigned short* bh = mixwTh + (long)(c0w + mrow) * 512 + kgrp * 8;
  const unsigned short* bl = mixwTl + (long)(c0w + mrow) * 512 + kgrp * 8;
  const unsigned short* ah = &rsh[mrow][kgrp * 8];
  const unsigned short* al = &rsl[mrow][kgrp * 8];
#pragma unroll
  for (int ks = 0; ks < 16; ++ks) {
    short8v aH = *(const short8v*)(ah + ks * 32);
    short8v aL = *(const short8v*)(al + ks * 32);
    short8v bH = *(const short8v*)(bh + ks * 32);
    short8v bL = *(const short8v*)(bl + ks * 32);
    acc = __builtin_amdgcn_mfma_f32_16x16x32_bf16(aH, bH, acc, 0, 0, 0);
    acc = __builtin_amdgcn_mfma_f32_16x16x32_bf16(aH, bL, acc, 0, 0, 0);
    acc = __builtin_amdgcn_mfma_f32_16x16x32_bf16(aL, bH, acc, 0, 0, 0);
  }
  // C/D: col = lane&15, row = (lane>>4)*4 + reg
#pragma unroll
  for (int reg = 0; reg < 4; ++reg) {
    int row = kgrp * 4 + reg;
    out[((long)b * NT + t0 + row) * NC + c0w + mrow] = acc[reg];
  }
}

extern "C" void kernel_launch(void* const* d_in, const int* in_sizes, int n_in,
                              void* d_out, int out_size, void* d_ws, size_t ws_size,
                              hipStream_t stream) {
  const float* x = (const float*)d_in[0];
  const float* W = (const float*)d_in[1];
  const float* bias = (const float*)d_in[2];
  const float* phiw = (const float*)d_in[3];
  const float* phib = (const float*)d_in[4];
  const float* anchor = (const float*)d_in[5];
  const float* logw = (const float*)d_in[6];
  const float* mixw = (const float*)d_in[7];
  const float* mixb = (const float*)d_in[8];
  float* out = (float*)d_out;

  float* ws = (float*)d_ws;
  float* Q = ws;                                     // 8*2049*128 = 2,098,176
  float* pi = Q + (long)NB * QROWS * NC;             // 4*2048*64  =   524,288
  float* eq = pi + (long)NS * NT * NLM;              // 32*2048*128= 8,388,608
  float* coefTT = eq + (long)NS * NB * NT * NC;      //               524,288
  float* rtb = coefTT + (long)NS * NCH * 4096;       //               524,288
  float* klocal = rtb + (long)NS * NCH * 4096;       //                 8,192
  float* kout = klocal + (long)NS * NCH * 64;        //                 8,192
  float* logZt = kout + (long)NS * NT;               //                 8,196
  float* S2 = logZt + (long)NS * QROWS;              //                32,768

  // pi is dead after k4 — reuse as bf16 mixwT hi/lo (2 x 65536 ushorts =
  // 65536 floats <= 524288).
  unsigned short* mixwTh = (unsigned short*)pi;
  unsigned short* mixwTl = (unsigned short*)(pi + 32768);

  hipLaunchKernelGGL(k1_uv, dim3(NB * NT / 16), dim3(256), 0, stream, x, W, bias, phiw, Q);
  hipLaunchKernelGGL(k23_sums_logz, dim3(260), dim3(128), 0, stream, Q, S2, logw, logZt);
  hipLaunchKernelGGL(kb_basis_fix, dim3(384), dim3(128), 0, stream, logw, logZt, pi, rtb, coefTT, klocal, Q, S2);
  hipLaunchKernelGGL(k4_e, dim3(NB, NT / 4, 2), dim3(256), 0, stream, Q, pi, phib, eq);
  hipLaunchKernelGGL(k0_prep, dim3(256), dim3(256), 0, stream, mixw, mixwTh, mixwTl);
  hipLaunchKernelGGL(k5a_data, dim3(NS * NB, NCH), dim3(128), 0, stream, rtb, eq);
  hipLaunchKernelGGL(k5b_scan, dim3(260), dim3(256), 0, stream, coefTT, klocal, eq, kout);
  hipLaunchKernelGGL(k6_mix, dim3(NB, NT / 16), dim3(512), 0, stream, eq, kout, anchor, mixwTh, mixwTl, mixb, out);
}